// Round 1
// baseline (9312.176 us; speedup 1.0000x reference)
//
#include <hip/hip_runtime.h>

// PCmer forward, fp32 correctness-first implementation.
// L=6, B=4, N=2048, D=512, H=8, DH=64, ID=512, M=266, INNER=1024, K=31.

#define L_LAYERS 6
#define B_ 4
#define N_ 2048
#define D_ 512
#define H_ 8
#define DH_ 64
#define M_ 266
#define INNER_ 1024
#define T_ 8192            // B*N tokens
#define ROWS_ 65536        // B*N*H rows for phi

__device__ __forceinline__ float wave_sum(float v) {
#pragma unroll
  for (int m = 1; m < 64; m <<= 1) v += __shfl_xor(v, m);
  return v;
}
__device__ __forceinline__ float wave_max(float v) {
#pragma unroll
  for (int m = 1; m < 64; m <<= 1) v = fmaxf(v, __shfl_xor(v, m));
  return v;
}

// ---------------- copy ----------------
__global__ void copy_kernel(const float4* __restrict__ in, float4* __restrict__ out, int n4) {
  int i = blockIdx.x * 256 + threadIdx.x;
  if (i < n4) out[i] = in[i];
}

// ---------------- layernorm (block per token, D=512) ----------------
__global__ __launch_bounds__(256) void ln_kernel(const float* __restrict__ x,
                                                 const float* __restrict__ g,
                                                 const float* __restrict__ b,
                                                 float* __restrict__ out) {
  const int t = blockIdx.x;
  const int tid = threadIdx.x;
  const float* row = x + (size_t)t * D_;
  float v0 = row[tid], v1 = row[tid + 256];
  float s1 = v0 + v1;
  float s2 = v0 * v0 + v1 * v1;
  s1 = wave_sum(s1);
  s2 = wave_sum(s2);
  __shared__ float sh1[4], sh2[4];
  int w = tid >> 6;
  if ((tid & 63) == 0) { sh1[w] = s1; sh2[w] = s2; }
  __syncthreads();
  s1 = sh1[0] + sh1[1] + sh1[2] + sh1[3];
  s2 = sh2[0] + sh2[1] + sh2[2] + sh2[3];
  float mu = s1 * (1.f / D_);
  float var = s2 * (1.f / D_) - mu * mu;
  float rs = rsqrtf(var + 1e-5f);
  out[(size_t)t * D_ + tid]       = (v0 - mu) * rs * g[tid] + b[tid];
  out[(size_t)t * D_ + tid + 256] = (v1 - mu) * rs * g[tid + 256] + b[tid + 256];
}

// ---------------- GEMM: C[t][n] = sum_k A[t][k]*W[n][k] + bias[n] (+res) ----------------
// 64x64 tile, BK=16, 256 threads, 4x4 per thread. T multiple of 64; N guarded; K multiple of 16.
template <bool HAS_RES>
__global__ __launch_bounds__(256) void gemm_bias(const float* __restrict__ A,
                                                 const float* __restrict__ W,
                                                 const float* __restrict__ bias,
                                                 const float* res, float* C,
                                                 int T, int N, int K) {
  __shared__ float As[16][68];
  __shared__ float Wsm[16][68];
  const int tid = threadIdx.x;
  const int tx = tid & 15, ty = tid >> 4;
  const int row0 = blockIdx.x * 64, col0 = blockIdx.y * 64;
  const int lr = tid >> 2;           // 0..63
  const int lc = (tid & 3) << 2;     // 0,4,8,12
  float acc[4][4] = {};
  for (int k0 = 0; k0 < K; k0 += 16) {
    float4 av = *(const float4*)(A + (size_t)(row0 + lr) * K + k0 + lc);
    float4 wv = make_float4(0.f, 0.f, 0.f, 0.f);
    int wr = col0 + lr;
    if (wr < N) wv = *(const float4*)(W + (size_t)wr * K + k0 + lc);
    As[lc + 0][lr] = av.x; As[lc + 1][lr] = av.y; As[lc + 2][lr] = av.z; As[lc + 3][lr] = av.w;
    Wsm[lc + 0][lr] = wv.x; Wsm[lc + 1][lr] = wv.y; Wsm[lc + 2][lr] = wv.z; Wsm[lc + 3][lr] = wv.w;
    __syncthreads();
#pragma unroll
    for (int kk = 0; kk < 16; ++kk) {
      const float4 a = *(const float4*)&As[kk][ty << 2];
      const float4 bb = *(const float4*)&Wsm[kk][tx << 2];
      acc[0][0] += a.x * bb.x; acc[0][1] += a.x * bb.y; acc[0][2] += a.x * bb.z; acc[0][3] += a.x * bb.w;
      acc[1][0] += a.y * bb.x; acc[1][1] += a.y * bb.y; acc[1][2] += a.y * bb.z; acc[1][3] += a.y * bb.w;
      acc[2][0] += a.z * bb.x; acc[2][1] += a.z * bb.y; acc[2][2] += a.z * bb.z; acc[2][3] += a.z * bb.w;
      acc[3][0] += a.w * bb.x; acc[3][1] += a.w * bb.y; acc[3][2] += a.w * bb.z; acc[3][3] += a.w * bb.w;
    }
    __syncthreads();
  }
#pragma unroll
  for (int i = 0; i < 4; i++) {
    const int r = row0 + (ty << 2) + i;
#pragma unroll
    for (int j = 0; j < 4; j++) {
      const int c = col0 + (tx << 2) + j;
      if (c < N) {
        float vv = acc[i][j];
        if (bias) vv += bias[c];
        if (HAS_RES) vv += res[(size_t)r * N + c];
        C[(size_t)r * N + c] = vv;
      }
    }
  }
}

// ---------------- phi epilogue: FAVOR softmax kernel features (wave per row) ----------------
// p holds raw dot products q_row . proj_m (row stride M). data = q or k rows (64 floats).
__global__ __launch_bounds__(256) void phi_epilogue(float* __restrict__ p,
                                                    const float* __restrict__ data,
                                                    int is_query) {
  const int t = blockIdx.x * 4 + (threadIdx.x >> 6);
  const int lane = threadIdx.x & 63;
  const float dn = 0.35355339059327373f;      // 64^-0.25
  const float ratio = 0.06131393394849658f;   // 266^-0.5
  float d = data[(size_t)t * DH_ + lane];
  float diag = 0.0625f * wave_sum(d * d);     // 0.5*dn^2 = 0.0625
  float* row = p + (size_t)t * M_;
  float vals[5];
  float mx = -1e30f;
#pragma unroll
  for (int i = 0; i < 5; i++) {
    int m = lane + (i << 6);
    float vv = (m < M_) ? dn * row[m] : -1e30f;
    vals[i] = vv;
    mx = fmaxf(mx, vv);
  }
  if (is_query) {
    mx = wave_max(mx);
#pragma unroll
    for (int i = 0; i < 5; i++) {
      int m = lane + (i << 6);
      if (m < M_) row[m] = ratio * (expf(vals[i] - diag - mx) + 1e-4f);
    }
  } else {
#pragma unroll
    for (int i = 0; i < 5; i++) {
      int m = lane + (i << 6);
      if (m < M_) row[m] = ratio * expf(vals[i] - diag + 1e-4f);
    }
  }
}

// ---------------- context: ctx[bh][m][e] = sum_n kp[b,n,h,m]*v[b,n,h,e]; ksum[bh][m] ----------------
// grid (B*H, 5 m-tiles), block 256: 64m x 64e outputs, 4x4/thread.
__global__ __launch_bounds__(256) void ctx_kernel(const float* __restrict__ kp,
                                                  const float* __restrict__ v,
                                                  float* __restrict__ ctx,
                                                  float* __restrict__ ksum) {
  __shared__ float kps[32][68];
  __shared__ float vs[32][68];
  const int bh = blockIdx.x, b = bh >> 3, h = bh & 7;
  const int m0 = blockIdx.y * 64;
  const int tid = threadIdx.x, tx = tid & 15, ty = tid >> 4;
  float acc[4][4] = {};
  float ks = 0.f;
  for (int n0 = 0; n0 < N_; n0 += 32) {
#pragma unroll
    for (int i = tid; i < 2048; i += 256) {
      int nn = i >> 6, mm = i & 63;
      int m = m0 + mm;
      size_t rowt = (size_t)((b * N_ + n0 + nn) * H_ + h);
      kps[nn][mm] = (m < M_) ? kp[rowt * M_ + m] : 0.f;
    }
#pragma unroll
    for (int i = tid; i < 2048; i += 256) {
      int nn = i >> 6, ee = i & 63;
      size_t rowt = (size_t)((b * N_ + n0 + nn) * H_ + h);
      vs[nn][ee] = v[rowt * DH_ + ee];
    }
    __syncthreads();
#pragma unroll
    for (int nn = 0; nn < 32; nn++) {
      const float4 a = *(const float4*)&kps[nn][ty << 2];
      const float4 bb = *(const float4*)&vs[nn][tx << 2];
      acc[0][0] += a.x * bb.x; acc[0][1] += a.x * bb.y; acc[0][2] += a.x * bb.z; acc[0][3] += a.x * bb.w;
      acc[1][0] += a.y * bb.x; acc[1][1] += a.y * bb.y; acc[1][2] += a.y * bb.z; acc[1][3] += a.y * bb.w;
      acc[2][0] += a.z * bb.x; acc[2][1] += a.z * bb.y; acc[2][2] += a.z * bb.z; acc[2][3] += a.z * bb.w;
      acc[3][0] += a.w * bb.x; acc[3][1] += a.w * bb.y; acc[3][2] += a.w * bb.z; acc[3][3] += a.w * bb.w;
    }
    if (tid < 64) {
#pragma unroll
      for (int nn = 0; nn < 32; nn++) ks += kps[nn][tid];
    }
    __syncthreads();
  }
#pragma unroll
  for (int i = 0; i < 4; i++) {
    int m = m0 + (ty << 2) + i;
    if (m < M_) {
#pragma unroll
      for (int j = 0; j < 4; j++)
        ctx[((size_t)bh * M_ + m) * DH_ + (tx << 2) + j] = acc[i][j];
    }
  }
  if (tid < 64 && (m0 + tid) < M_) ksum[bh * M_ + m0 + tid] = ks;
}

// ---------------- d_inv (wave per row) ----------------
__global__ __launch_bounds__(256) void dinv_kernel(const float* __restrict__ qp,
                                                   const float* __restrict__ ksum,
                                                   float* __restrict__ dinv) {
  const int t = blockIdx.x * 4 + (threadIdx.x >> 6);  // t = (b*N+n)*H+h
  const int lane = threadIdx.x & 63;
  const int h = t & 7;
  const int b = t >> 14;  // / (N*H)
  const float* row = qp + (size_t)t * M_;
  const float* kr = ksum + (size_t)(b * H_ + h) * M_;
  float acc = 0.f;
#pragma unroll
  for (int i = 0; i < 5; i++) {
    int m = lane + (i << 6);
    if (m < M_) acc += row[m] * kr[m];
  }
  acc = wave_sum(acc);
  if (lane == 0) dinv[t] = 1.f / (acc + 1e-8f);
}

// ---------------- attention out: o[b,n,h,e] = dinv * sum_m qp[n,m]*ctx[m,e] ----------------
// grid (B*H, N/64), block 256: 64n x 64e, 4x4/thread.
__global__ __launch_bounds__(256) void attn_out_kernel(const float* __restrict__ qp,
                                                       const float* __restrict__ ctx,
                                                       const float* __restrict__ dinv,
                                                       float* __restrict__ o) {
  __shared__ float qs[64][33];
  __shared__ float cs[32][68];
  const int bh = blockIdx.x, b = bh >> 3, h = bh & 7;
  const int n0 = blockIdx.y * 64;
  const int tid = threadIdx.x, tx = tid & 15, ty = tid >> 4;
  float acc[4][4] = {};
  for (int m0 = 0; m0 < 288; m0 += 32) {
#pragma unroll
    for (int i = tid; i < 2048; i += 256) {
      int nn = i >> 5, mm = i & 31;
      int m = m0 + mm;
      size_t rowt = (size_t)((b * N_ + n0 + nn) * H_ + h);
      qs[nn][mm] = (m < M_) ? qp[rowt * M_ + m] : 0.f;
    }
#pragma unroll
    for (int i = tid; i < 2048; i += 256) {
      int mm = i >> 6, ee = i & 63;
      int m = m0 + mm;
      cs[mm][ee] = (m < M_) ? ctx[((size_t)bh * M_ + m) * DH_ + ee] : 0.f;
    }
    __syncthreads();
#pragma unroll
    for (int mm = 0; mm < 32; mm++) {
      const float4 bb = *(const float4*)&cs[mm][tx << 2];
      float a0 = qs[(ty << 2) + 0][mm];
      float a1 = qs[(ty << 2) + 1][mm];
      float a2 = qs[(ty << 2) + 2][mm];
      float a3 = qs[(ty << 2) + 3][mm];
      acc[0][0] += a0 * bb.x; acc[0][1] += a0 * bb.y; acc[0][2] += a0 * bb.z; acc[0][3] += a0 * bb.w;
      acc[1][0] += a1 * bb.x; acc[1][1] += a1 * bb.y; acc[1][2] += a1 * bb.z; acc[1][3] += a1 * bb.w;
      acc[2][0] += a2 * bb.x; acc[2][1] += a2 * bb.y; acc[2][2] += a2 * bb.z; acc[2][3] += a2 * bb.w;
      acc[3][0] += a3 * bb.x; acc[3][1] += a3 * bb.y; acc[3][2] += a3 * bb.z; acc[3][3] += a3 * bb.w;
    }
    __syncthreads();
  }
#pragma unroll
  for (int i = 0; i < 4; i++) {
    int n = n0 + (ty << 2) + i;
    size_t rowt = (size_t)((b * N_ + n) * H_ + h);
    float di = dinv[rowt];
#pragma unroll
    for (int j = 0; j < 4; j++)
      o[rowt * DH_ + (tx << 2) + j] = acc[i][j] * di;
  }
}

// ---------------- GLU: out[t,c] = a * sigmoid(g), a=y[t,c], g=y[t,c+1024] ----------------
__global__ void glu_kernel(const float* __restrict__ y, float* __restrict__ out) {
  int i = blockIdx.x * 256 + threadIdx.x;  // over T*1024/4
  const float4* y4 = (const float4*)y;
  int t = i >> 8, c4 = i & 255;
  float4 a = y4[(size_t)t * 512 + c4];
  float4 g = y4[(size_t)t * 512 + 256 + c4];
  float4 r;
  r.x = a.x / (1.f + expf(-g.x));
  r.y = a.y / (1.f + expf(-g.y));
  r.z = a.z / (1.f + expf(-g.z));
  r.w = a.w / (1.f + expf(-g.w));
  ((float4*)out)[i] = r;
}

// ---------------- depthwise conv K=31, pad 15, + bias + silu ----------------
__global__ void dwconv_kernel(const float* __restrict__ x, const float* __restrict__ w,
                              const float* __restrict__ bias, float* __restrict__ out) {
  int i = blockIdx.x * 256 + threadIdx.x;  // B*N*1024
  int c = i & 1023;
  int bn = i >> 10;
  int n = bn & 2047;
  int b = bn >> 11;
  float acc = bias[c];
  const float* wc = w + c * 31;
#pragma unroll
  for (int kk = 0; kk < 31; kk++) {
    int nn = n + kk - 15;
    if (nn >= 0 && nn < N_) acc += x[(size_t)(b * N_ + nn) * INNER_ + c] * wc[kk];
  }
  out[i] = acc / (1.f + expf(-acc));  // silu
}

// ---------------- host ----------------
extern "C" void kernel_launch(void* const* d_in, const int* in_sizes, int n_in,
                              void* d_out, int out_size, void* d_ws, size_t ws_size,
                              hipStream_t stream) {
  const float* in_x  = (const float*)d_in[0];
  const float* ln1_g = (const float*)d_in[1];
  const float* ln1_b = (const float*)d_in[2];
  const float* wq    = (const float*)d_in[3];
  const float* bq    = (const float*)d_in[4];
  const float* wk    = (const float*)d_in[5];
  const float* bk    = (const float*)d_in[6];
  const float* wv    = (const float*)d_in[7];
  const float* bv    = (const float*)d_in[8];
  const float* wo    = (const float*)d_in[9];
  const float* bo    = (const float*)d_in[10];
  const float* proj  = (const float*)d_in[11];
  const float* ln2_g = (const float*)d_in[12];
  const float* ln2_b = (const float*)d_in[13];
  const float* pw1_w = (const float*)d_in[14];
  const float* pw1_b = (const float*)d_in[15];
  const float* dw_w  = (const float*)d_in[16];
  const float* dw_b  = (const float*)d_in[17];
  const float* pw2_w = (const float*)d_in[18];
  const float* pw2_b = (const float*)d_in[19];

  float* ws = (float*)d_ws;
  float* x    = ws;                               // T*512
  float* h    = x + (size_t)T_ * D_;              // T*512 (also attention out o)
  float* q    = h + (size_t)T_ * D_;              // T*512
  float* k    = q + (size_t)T_ * D_;              // T*512
  float* v    = k + (size_t)T_ * D_;              // T*512
  float* p    = v + (size_t)T_ * D_;              // 65536*266 (kp then qp; later glu+conv)
  float* ctx  = p + (size_t)ROWS_ * M_;           // 32*266*64
  float* ksum = ctx + (size_t)B_ * H_ * M_ * DH_; // 32*266
  float* dinv = ksum + (size_t)B_ * H_ * M_;      // 65536
  float* y    = dinv + (size_t)ROWS_;             // T*2048
  float* glu  = p;                                // reuse p (free after attention)
  float* conv = p + (size_t)T_ * INNER_;          // reuse p second half

  // x = input
  {
    int n4 = T_ * D_ / 4;
    copy_kernel<<<dim3((n4 + 255) / 256), 256, 0, stream>>>((const float4*)in_x, (float4*)x, n4);
  }

  for (int l = 0; l < L_LAYERS; l++) {
    const float* wql = wq + (size_t)l * D_ * D_;
    const float* wkl = wk + (size_t)l * D_ * D_;
    const float* wvl = wv + (size_t)l * D_ * D_;
    const float* wol = wo + (size_t)l * D_ * D_;
    const float* projl = proj + (size_t)l * M_ * DH_;
    const float* pw1l = pw1_w + (size_t)l * 2048 * D_;
    const float* dwl  = dw_w + (size_t)l * INNER_ * 31;
    const float* pw2l = pw2_w + (size_t)l * D_ * INNER_;

    // h = LN1(x)
    ln_kernel<<<T_, 256, 0, stream>>>(x, ln1_g + l * D_, ln1_b + l * D_, h);
    // q,k,v = h @ W^T + b   (layout (B,N,H,DH) = (T,512))
    gemm_bias<false><<<dim3(T_ / 64, 8), 256, 0, stream>>>(h, wql, bq + l * D_, nullptr, q, T_, D_, D_);
    gemm_bias<false><<<dim3(T_ / 64, 8), 256, 0, stream>>>(h, wkl, bk + l * D_, nullptr, k, T_, D_, D_);
    gemm_bias<false><<<dim3(T_ / 64, 8), 256, 0, stream>>>(h, wvl, bv + l * D_, nullptr, v, T_, D_, D_);
    // kp features
    gemm_bias<false><<<dim3(ROWS_ / 64, 5), 256, 0, stream>>>(k, projl, nullptr, nullptr, p, ROWS_, M_, DH_);
    phi_epilogue<<<ROWS_ / 4, 256, 0, stream>>>(p, k, 0);
    ctx_kernel<<<dim3(B_ * H_, 5), 256, 0, stream>>>(p, v, ctx, ksum);
    // qp features
    gemm_bias<false><<<dim3(ROWS_ / 64, 5), 256, 0, stream>>>(q, projl, nullptr, nullptr, p, ROWS_, M_, DH_);
    phi_epilogue<<<ROWS_ / 4, 256, 0, stream>>>(p, q, 1);
    dinv_kernel<<<ROWS_ / 4, 256, 0, stream>>>(p, ksum, dinv);
    attn_out_kernel<<<dim3(B_ * H_, N_ / 64), 256, 0, stream>>>(p, ctx, dinv, h);
    // x = x + o @ wo^T + bo
    gemm_bias<true><<<dim3(T_ / 64, 8), 256, 0, stream>>>(h, wol, bo + l * D_, x, x, T_, D_, D_);
    // FF branch
    ln_kernel<<<T_, 256, 0, stream>>>(x, ln2_g + l * D_, ln2_b + l * D_, h);
    gemm_bias<false><<<dim3(T_ / 64, 32), 256, 0, stream>>>(h, pw1l, pw1_b + l * 2048, nullptr, y, T_, 2048, D_);
    glu_kernel<<<T_ * INNER_ / 4 / 256, 256, 0, stream>>>(y, glu);
    dwconv_kernel<<<T_ * INNER_ / 256, 256, 0, stream>>>(glu, dwl, dw_b + l * INNER_, conv);
    // x = x + dw @ pw2^T + b
    gemm_bias<true><<<dim3(T_ / 64, 8), 256, 0, stream>>>(conv, pw2l, pw2_b + l * D_, x, x, T_, D_, INNER_);
  }

  // d_out = x
  {
    int n4 = T_ * D_ / 4;
    copy_kernel<<<dim3((n4 + 255) / 256), 256, 0, stream>>>((const float4*)x, (float4*)d_out, n4);
  }
}

// Round 2
// 4352.337 us; speedup vs baseline: 2.1396x; 2.1396x over previous
//
#include <hip/hip_runtime.h>

// PCmer forward: bf16-MFMA GEMMs + fp32 residual stream.
// L=6, B=4, N=2048, D=512, H=8, DH=64, ID=512, M=266, INNER=1024, K=31.

#define L_LAYERS 6
#define B_ 4
#define N_ 2048
#define D_ 512
#define H_ 8
#define DH_ 64
#define M_ 266
#define INNER_ 1024
#define T_ 8192            // B*N tokens
#define ROWS_ 65536        // B*N*H rows for phi

typedef __attribute__((ext_vector_type(8))) short short8;
typedef __attribute__((ext_vector_type(4))) float floatx4;

__device__ __forceinline__ ushort f2bf(float f) {
  union { float f; uint u; } v; v.f = f;
  uint r = v.u + 0x7fffu + ((v.u >> 16) & 1u);
  return (ushort)(r >> 16);
}
__device__ __forceinline__ float bf2f(ushort u) {
  union { uint u; float f; } v; v.u = ((uint)u) << 16;
  return v.f;
}

__device__ __forceinline__ float wave_sum(float v) {
#pragma unroll
  for (int m = 1; m < 64; m <<= 1) v += __shfl_xor(v, m);
  return v;
}
__device__ __forceinline__ float wave_max(float v) {
#pragma unroll
  for (int m = 1; m < 64; m <<= 1) v = fmaxf(v, __shfl_xor(v, m));
  return v;
}

// ---------------- copy / convert ----------------
__global__ void copy_kernel(const float4* __restrict__ in, float4* __restrict__ out, int n4) {
  int i = blockIdx.x * 256 + threadIdx.x;
  if (i < n4) out[i] = in[i];
}
__global__ void f2bf4_kernel(const float4* __restrict__ in, ushort* __restrict__ out, int n4) {
  int i = blockIdx.x * 256 + threadIdx.x;
  if (i < n4) {
    float4 v = in[i];
    ushort4 r;
    r.x = f2bf(v.x); r.y = f2bf(v.y); r.z = f2bf(v.z); r.w = f2bf(v.w);
    *(ushort4*)(out + (size_t)i * 4) = r;
  }
}

// ---------------- layernorm (block per token, D=512), bf16 out ----------------
__global__ __launch_bounds__(256) void ln_kernel(const float* __restrict__ x,
                                                 const float* __restrict__ g,
                                                 const float* __restrict__ b,
                                                 ushort* __restrict__ out) {
  const int t = blockIdx.x;
  const int tid = threadIdx.x;
  const float* row = x + (size_t)t * D_;
  float v0 = row[tid], v1 = row[tid + 256];
  float s1 = v0 + v1;
  float s2 = v0 * v0 + v1 * v1;
  s1 = wave_sum(s1);
  s2 = wave_sum(s2);
  __shared__ float sh1[4], sh2[4];
  int w = tid >> 6;
  if ((tid & 63) == 0) { sh1[w] = s1; sh2[w] = s2; }
  __syncthreads();
  s1 = sh1[0] + sh1[1] + sh1[2] + sh1[3];
  s2 = sh2[0] + sh2[1] + sh2[2] + sh2[3];
  float mu = s1 * (1.f / D_);
  float var = s2 * (1.f / D_) - mu * mu;
  float rs = rsqrtf(var + 1e-5f);
  out[(size_t)t * D_ + tid]       = f2bf((v0 - mu) * rs * g[tid] + b[tid]);
  out[(size_t)t * D_ + tid + 256] = f2bf((v1 - mu) * rs * g[tid + 256] + b[tid + 256]);
}

// ---------------- bf16 MFMA GEMM: C[t][n] = sum_k A[t][k]*W[n][k] + bias + res ----------------
// A: [T][K] bf16, W: [Nn][K] bf16 (both K-contiguous). 128x128 tile, BK=32, 256 thr = 4 waves,
// each wave one 64x64 quadrant (4x4 of 16x16x32 MFMA). T % 128 == 0, K % 32 == 0; Nn guarded.
template <bool HAS_RES, bool OUT_BF16>
__global__ __launch_bounds__(256) void gemm_mfma(const ushort* __restrict__ A,
                                                 const ushort* __restrict__ W,
                                                 const float* __restrict__ bias,
                                                 const float* __restrict__ res,
                                                 void* __restrict__ Cout,
                                                 int T, int Nn, int K) {
  __shared__ ushort As[128][40];   // +8 pad (16B) to break bank strides
  __shared__ ushort Bs[128][40];
  const int tid = threadIdx.x;
  const int row0 = blockIdx.x * 128, col0 = blockIdx.y * 128;
  // staging: thread -> (row 0..127, k-half 0/1)
  const int srow = tid >> 1;
  const int skh = (tid & 1) << 4;  // ushort offset 0 or 16
  const ushort* gA = A + (size_t)(row0 + srow) * K + skh;
  const int wrow = col0 + srow;
  const ushort* gW = W + (size_t)wrow * K + skh;
  const bool wok = wrow < Nn;
  // compute mapping
  const int w = tid >> 6;
  const int lane = tid & 63;
  const int m16 = lane & 15;
  const int quad = lane >> 4;
  const int awr = (w >> 1) * 64;
  const int bwc = (w & 1) * 64;
  floatx4 acc[4][4] = {};
  const uint4 zz = make_uint4(0, 0, 0, 0);
  for (int k0 = 0; k0 < K; k0 += 32) {
    uint4 a0 = *(const uint4*)(gA + k0);
    uint4 a1 = *(const uint4*)(gA + k0 + 8);
    uint4 w0 = wok ? *(const uint4*)(gW + k0) : zz;
    uint4 w1 = wok ? *(const uint4*)(gW + k0 + 8) : zz;
    __syncthreads();
    *(uint4*)&As[srow][skh] = a0;
    *(uint4*)&As[srow][skh + 8] = a1;
    *(uint4*)&Bs[srow][skh] = w0;
    *(uint4*)&Bs[srow][skh + 8] = w1;
    __syncthreads();
    short8 af[4], bfr[4];
#pragma unroll
    for (int i = 0; i < 4; i++) af[i] = *(const short8*)&As[awr + i * 16 + m16][quad * 8];
#pragma unroll
    for (int j = 0; j < 4; j++) bfr[j] = *(const short8*)&Bs[bwc + j * 16 + m16][quad * 8];
#pragma unroll
    for (int i = 0; i < 4; i++)
#pragma unroll
      for (int j = 0; j < 4; j++)
        acc[i][j] = __builtin_amdgcn_mfma_f32_16x16x32_bf16(af[i], bfr[j], acc[i][j], 0, 0, 0);
  }
#pragma unroll
  for (int i = 0; i < 4; i++) {
    const int r0 = row0 + awr + i * 16 + quad * 4;
#pragma unroll
    for (int j = 0; j < 4; j++) {
      const int c = col0 + bwc + j * 16 + m16;
      if (c < Nn) {
        const float bv = bias ? bias[c] : 0.f;
#pragma unroll
        for (int r = 0; r < 4; r++) {
          float vv = acc[i][j][r] + bv;
          if (HAS_RES) vv += res[(size_t)(r0 + r) * Nn + c];
          if (OUT_BF16) ((ushort*)Cout)[(size_t)(r0 + r) * Nn + c] = f2bf(vv);
          else          ((float*)Cout)[(size_t)(r0 + r) * Nn + c] = vv;
        }
      }
    }
  }
}

// ---------------- phi epilogue: FAVOR softmax kernel features (wave per row) ----------------
__global__ __launch_bounds__(256) void phi_epilogue(float* __restrict__ p,
                                                    const ushort* __restrict__ data,
                                                    int is_query) {
  const int t = blockIdx.x * 4 + (threadIdx.x >> 6);
  const int lane = threadIdx.x & 63;
  const float dn = 0.35355339059327373f;      // 64^-0.25
  const float ratio = 0.06131393394849658f;   // 266^-0.5
  float d = bf2f(data[(size_t)t * DH_ + lane]);
  float diag = 0.0625f * wave_sum(d * d);     // 0.5*dn^2 = 0.0625
  float* row = p + (size_t)t * M_;
  float vals[5];
  float mx = -1e30f;
#pragma unroll
  for (int i = 0; i < 5; i++) {
    int m = lane + (i << 6);
    float vv = (m < M_) ? dn * row[m] : -1e30f;
    vals[i] = vv;
    mx = fmaxf(mx, vv);
  }
  if (is_query) {
    mx = wave_max(mx);
#pragma unroll
    for (int i = 0; i < 5; i++) {
      int m = lane + (i << 6);
      if (m < M_) row[m] = ratio * (expf(vals[i] - diag - mx) + 1e-4f);
    }
  } else {
#pragma unroll
    for (int i = 0; i < 5; i++) {
      int m = lane + (i << 6);
      if (m < M_) row[m] = ratio * expf(vals[i] - diag + 1e-4f);
    }
  }
}

// ---------------- context: ctx[bh][m][e] = sum_n kp[b,n,h,m]*v[b,n,h,e]; ksum[bh][m] ----------------
__global__ __launch_bounds__(256) void ctx_kernel(const float* __restrict__ kp,
                                                  const ushort* __restrict__ v,
                                                  float* __restrict__ ctx,
                                                  float* __restrict__ ksum) {
  __shared__ float kps[32][68];
  __shared__ float vs[32][68];
  const int bh = blockIdx.x, b = bh >> 3, h = bh & 7;
  const int m0 = blockIdx.y * 64;
  const int tid = threadIdx.x, tx = tid & 15, ty = tid >> 4;
  float acc[4][4] = {};
  float ks = 0.f;
  for (int n0 = 0; n0 < N_; n0 += 32) {
#pragma unroll
    for (int i = tid; i < 2048; i += 256) {
      int nn = i >> 6, mm = i & 63;
      int m = m0 + mm;
      size_t rowt = (size_t)((b * N_ + n0 + nn) * H_ + h);
      kps[nn][mm] = (m < M_) ? kp[rowt * M_ + m] : 0.f;
    }
#pragma unroll
    for (int i = tid; i < 2048; i += 256) {
      int nn = i >> 6, ee = i & 63;
      size_t rowt = (size_t)((b * N_ + n0 + nn) * H_ + h);
      vs[nn][ee] = bf2f(v[rowt * DH_ + ee]);
    }
    __syncthreads();
#pragma unroll
    for (int nn = 0; nn < 32; nn++) {
      const float4 a = *(const float4*)&kps[nn][ty << 2];
      const float4 bb = *(const float4*)&vs[nn][tx << 2];
      acc[0][0] += a.x * bb.x; acc[0][1] += a.x * bb.y; acc[0][2] += a.x * bb.z; acc[0][3] += a.x * bb.w;
      acc[1][0] += a.y * bb.x; acc[1][1] += a.y * bb.y; acc[1][2] += a.y * bb.z; acc[1][3] += a.y * bb.w;
      acc[2][0] += a.z * bb.x; acc[2][1] += a.z * bb.y; acc[2][2] += a.z * bb.z; acc[2][3] += a.z * bb.w;
      acc[3][0] += a.w * bb.x; acc[3][1] += a.w * bb.y; acc[3][2] += a.w * bb.z; acc[3][3] += a.w * bb.w;
    }
    if (tid < 64) {
#pragma unroll
      for (int nn = 0; nn < 32; nn++) ks += kps[nn][tid];
    }
    __syncthreads();
  }
#pragma unroll
  for (int i = 0; i < 4; i++) {
    int m = m0 + (ty << 2) + i;
    if (m < M_) {
#pragma unroll
      for (int j = 0; j < 4; j++)
        ctx[((size_t)bh * M_ + m) * DH_ + (tx << 2) + j] = acc[i][j];
    }
  }
  if (tid < 64 && (m0 + tid) < M_) ksum[bh * M_ + m0 + tid] = ks;
}

// ---------------- d_inv (wave per row) ----------------
__global__ __launch_bounds__(256) void dinv_kernel(const float* __restrict__ qp,
                                                   const float* __restrict__ ksum,
                                                   float* __restrict__ dinv) {
  const int t = blockIdx.x * 4 + (threadIdx.x >> 6);  // t = (b*N+n)*H+h
  const int lane = threadIdx.x & 63;
  const int h = t & 7;
  const int b = t >> 14;
  const float* row = qp + (size_t)t * M_;
  const float* kr = ksum + (size_t)(b * H_ + h) * M_;
  float acc = 0.f;
#pragma unroll
  for (int i = 0; i < 5; i++) {
    int m = lane + (i << 6);
    if (m < M_) acc += row[m] * kr[m];
  }
  acc = wave_sum(acc);
  if (lane == 0) dinv[t] = 1.f / (acc + 1e-8f);
}

// ---------------- attention out: o[b,n,h,e] = dinv * sum_m qp[n,m]*ctx[m,e], bf16 out ---------
__global__ __launch_bounds__(256) void attn_out_kernel(const float* __restrict__ qp,
                                                       const float* __restrict__ ctx,
                                                       const float* __restrict__ dinv,
                                                       ushort* __restrict__ o) {
  __shared__ float qs[64][33];
  __shared__ float cs[32][68];
  const int bh = blockIdx.x, b = bh >> 3, h = bh & 7;
  const int n0 = blockIdx.y * 64;
  const int tid = threadIdx.x, tx = tid & 15, ty = tid >> 4;
  float acc[4][4] = {};
  for (int m0 = 0; m0 < 288; m0 += 32) {
#pragma unroll
    for (int i = tid; i < 2048; i += 256) {
      int nn = i >> 5, mm = i & 31;
      int m = m0 + mm;
      size_t rowt = (size_t)((b * N_ + n0 + nn) * H_ + h);
      qs[nn][mm] = (m < M_) ? qp[rowt * M_ + m] : 0.f;
    }
#pragma unroll
    for (int i = tid; i < 2048; i += 256) {
      int mm = i >> 6, ee = i & 63;
      int m = m0 + mm;
      cs[mm][ee] = (m < M_) ? ctx[((size_t)bh * M_ + m) * DH_ + ee] : 0.f;
    }
    __syncthreads();
#pragma unroll
    for (int mm = 0; mm < 32; mm++) {
      const float4 bb = *(const float4*)&cs[mm][tx << 2];
      float a0 = qs[(ty << 2) + 0][mm];
      float a1 = qs[(ty << 2) + 1][mm];
      float a2 = qs[(ty << 2) + 2][mm];
      float a3 = qs[(ty << 2) + 3][mm];
      acc[0][0] += a0 * bb.x; acc[0][1] += a0 * bb.y; acc[0][2] += a0 * bb.z; acc[0][3] += a0 * bb.w;
      acc[1][0] += a1 * bb.x; acc[1][1] += a1 * bb.y; acc[1][2] += a1 * bb.z; acc[1][3] += a1 * bb.w;
      acc[2][0] += a2 * bb.x; acc[2][1] += a2 * bb.y; acc[2][2] += a2 * bb.z; acc[2][3] += a2 * bb.w;
      acc[3][0] += a3 * bb.x; acc[3][1] += a3 * bb.y; acc[3][2] += a3 * bb.z; acc[3][3] += a3 * bb.w;
    }
    __syncthreads();
  }
#pragma unroll
  for (int i = 0; i < 4; i++) {
    int n = n0 + (ty << 2) + i;
    size_t rowt = (size_t)((b * N_ + n) * H_ + h);
    float di = dinv[rowt];
#pragma unroll
    for (int j = 0; j < 4; j++)
      o[rowt * DH_ + (tx << 2) + j] = f2bf(acc[i][j] * di);
  }
}

// ---------------- GLU: out[t,c] = a * sigmoid(g) ----------------
__global__ void glu_kernel(const float* __restrict__ y, float* __restrict__ out) {
  int i = blockIdx.x * 256 + threadIdx.x;  // over T*1024/4
  const float4* y4 = (const float4*)y;
  int t = i >> 8, c4 = i & 255;
  float4 a = y4[(size_t)t * 512 + c4];
  float4 g = y4[(size_t)t * 512 + 256 + c4];
  float4 r;
  r.x = a.x / (1.f + expf(-g.x));
  r.y = a.y / (1.f + expf(-g.y));
  r.z = a.z / (1.f + expf(-g.z));
  r.w = a.w / (1.f + expf(-g.w));
  ((float4*)out)[i] = r;
}

// ---------------- depthwise conv K=31, pad 15, + bias + silu; bf16 out ----------------
// Register sliding window: thread owns (b, channel c, 16 n-positions).
#define TN_ 16
__global__ __launch_bounds__(256) void dwconv_kernel(const float* __restrict__ x,
                                                     const float* __restrict__ w,
                                                     const float* __restrict__ bias,
                                                     ushort* __restrict__ out) {
  const int bid = blockIdx.x;
  const int cb = bid & 3;            // 4 channel blocks of 256
  const int nb = (bid >> 2) & 127;   // 128 n blocks of TN_
  const int b  = bid >> 9;           // batch
  const int c = cb * 256 + threadIdx.x;
  const int n0 = nb * TN_;
  float win[TN_ + 30];
#pragma unroll
  for (int i = 0; i < TN_ + 30; i++) {
    int nn = n0 + i - 15;
    win[i] = (nn >= 0 && nn < N_) ? x[(size_t)(b * N_ + nn) * INNER_ + c] : 0.f;
  }
  float wc[31];
#pragma unroll
  for (int kk = 0; kk < 31; kk++) wc[kk] = w[c * 31 + kk];
  const float bsv = bias[c];
#pragma unroll
  for (int j = 0; j < TN_; j++) {
    float acc = bsv;
#pragma unroll
    for (int kk = 0; kk < 31; kk++) acc += win[j + kk] * wc[kk];
    acc = acc / (1.f + expf(-acc));  // silu
    out[(size_t)(b * N_ + n0 + j) * INNER_ + c] = f2bf(acc);
  }
}

// ---------------- host ----------------
extern "C" void kernel_launch(void* const* d_in, const int* in_sizes, int n_in,
                              void* d_out, int out_size, void* d_ws, size_t ws_size,
                              hipStream_t stream) {
  const float* in_x  = (const float*)d_in[0];
  const float* ln1_g = (const float*)d_in[1];
  const float* ln1_b = (const float*)d_in[2];
  const float* wq    = (const float*)d_in[3];
  const float* bq    = (const float*)d_in[4];
  const float* wk    = (const float*)d_in[5];
  const float* bk    = (const float*)d_in[6];
  const float* wv    = (const float*)d_in[7];
  const float* bv    = (const float*)d_in[8];
  const float* wo    = (const float*)d_in[9];
  const float* bo    = (const float*)d_in[10];
  const float* proj  = (const float*)d_in[11];
  const float* ln2_g = (const float*)d_in[12];
  const float* ln2_b = (const float*)d_in[13];
  const float* pw1_w = (const float*)d_in[14];
  const float* pw1_b = (const float*)d_in[15];
  const float* dw_w  = (const float*)d_in[16];
  const float* dw_b  = (const float*)d_in[17];
  const float* pw2_w = (const float*)d_in[18];
  const float* pw2_b = (const float*)d_in[19];

  char* cur = (char*)d_ws;
  auto alloc = [&](size_t bytes) { char* p = cur; cur += (bytes + 255) & ~(size_t)255; return p; };
  float*  x    = (float*)alloc((size_t)T_ * D_ * 4);
  float*  p    = (float*)alloc((size_t)ROWS_ * M_ * 4);
  float*  ctx  = (float*)alloc((size_t)B_ * H_ * M_ * DH_ * 4);
  float*  ksum = (float*)alloc((size_t)B_ * H_ * M_ * 4);
  float*  dinv = (float*)alloc((size_t)ROWS_ * 4);
  float*  y    = (float*)alloc((size_t)T_ * 2048 * 4);
  ushort* h    = (ushort*)alloc((size_t)T_ * D_ * 2);
  ushort* q    = (ushort*)alloc((size_t)T_ * D_ * 2);
  ushort* k    = (ushort*)alloc((size_t)T_ * D_ * 2);
  ushort* v    = (ushort*)alloc((size_t)T_ * D_ * 2);
  ushort* obuf = (ushort*)alloc((size_t)T_ * D_ * 2);
  ushort* wq_b = (ushort*)alloc((size_t)L_LAYERS * D_ * D_ * 2);
  ushort* wk_b = (ushort*)alloc((size_t)L_LAYERS * D_ * D_ * 2);
  ushort* wv_b = (ushort*)alloc((size_t)L_LAYERS * D_ * D_ * 2);
  ushort* wo_b = (ushort*)alloc((size_t)L_LAYERS * D_ * D_ * 2);
  ushort* pj_b = (ushort*)alloc((size_t)L_LAYERS * M_ * DH_ * 2);
  ushort* p1_b = (ushort*)alloc((size_t)L_LAYERS * 2048 * D_ * 2);
  ushort* p2_b = (ushort*)alloc((size_t)L_LAYERS * D_ * INNER_ * 2);
  // glu (fp32) and conv (bf16) reuse the p region (free between attention and FF use of p)
  float*  glu  = p;                                  // T*1024 fp32 = 33.5 MB
  ushort* conv = (ushort*)((char*)p + (size_t)T_ * INNER_ * 4);  // T*1024 bf16

  // weight conversions (same work every call; graph-capture safe)
  auto conv_w = [&](const float* src, ushort* dst, size_t n) {
    int n4 = (int)(n / 4);
    f2bf4_kernel<<<(n4 + 255) / 256, 256, 0, stream>>>((const float4*)src, dst, n4);
  };
  conv_w(wq, wq_b, (size_t)L_LAYERS * D_ * D_);
  conv_w(wk, wk_b, (size_t)L_LAYERS * D_ * D_);
  conv_w(wv, wv_b, (size_t)L_LAYERS * D_ * D_);
  conv_w(wo, wo_b, (size_t)L_LAYERS * D_ * D_);
  conv_w(proj, pj_b, (size_t)L_LAYERS * M_ * DH_);
  conv_w(pw1_w, p1_b, (size_t)L_LAYERS * 2048 * D_);
  conv_w(pw2_w, p2_b, (size_t)L_LAYERS * D_ * INNER_);

  {
    int n4 = T_ * D_ / 4;
    copy_kernel<<<(n4 + 255) / 256, 256, 0, stream>>>((const float4*)in_x, (float4*)x, n4);
  }

  for (int l = 0; l < L_LAYERS; l++) {
    const ushort* wql = wq_b + (size_t)l * D_ * D_;
    const ushort* wkl = wk_b + (size_t)l * D_ * D_;
    const ushort* wvl = wv_b + (size_t)l * D_ * D_;
    const ushort* wol = wo_b + (size_t)l * D_ * D_;
    const ushort* pjl = pj_b + (size_t)l * M_ * DH_;
    const ushort* p1l = p1_b + (size_t)l * 2048 * D_;
    const ushort* p2l = p2_b + (size_t)l * D_ * INNER_;
    const float*  dwl = dw_w + (size_t)l * INNER_ * 31;

    // h = LN1(x) -> bf16
    ln_kernel<<<T_, 256, 0, stream>>>(x, ln1_g + l * D_, ln1_b + l * D_, h);
    // q,k,v = h @ W^T + b  -> bf16 (layout (B,N,H,DH) = (T,512))
    gemm_mfma<false, true><<<dim3(T_ / 128, 4), 256, 0, stream>>>(h, wql, bq + l * D_, nullptr, q, T_, D_, D_);
    gemm_mfma<false, true><<<dim3(T_ / 128, 4), 256, 0, stream>>>(h, wkl, bk + l * D_, nullptr, k, T_, D_, D_);
    gemm_mfma<false, true><<<dim3(T_ / 128, 4), 256, 0, stream>>>(h, wvl, bv + l * D_, nullptr, v, T_, D_, D_);
    // kp features: p = k @ proj^T (fp32 out), epilogue, context
    gemm_mfma<false, false><<<dim3(ROWS_ / 128, 3), 256, 0, stream>>>(k, pjl, nullptr, nullptr, p, ROWS_, M_, DH_);
    phi_epilogue<<<ROWS_ / 4, 256, 0, stream>>>(p, k, 0);
    ctx_kernel<<<dim3(B_ * H_, 5), 256, 0, stream>>>(p, v, ctx, ksum);
    // qp features
    gemm_mfma<false, false><<<dim3(ROWS_ / 128, 3), 256, 0, stream>>>(q, pjl, nullptr, nullptr, p, ROWS_, M_, DH_);
    phi_epilogue<<<ROWS_ / 4, 256, 0, stream>>>(p, q, 1);
    dinv_kernel<<<ROWS_ / 4, 256, 0, stream>>>(p, ksum, dinv);
    attn_out_kernel<<<dim3(B_ * H_, N_ / 64), 256, 0, stream>>>(p, ctx, dinv, obuf);
    // x = x + o @ wo^T + bo
    gemm_mfma<true, false><<<dim3(T_ / 128, 4), 256, 0, stream>>>(obuf, wol, bo + l * D_, x, x, T_, D_, D_);
    // FF branch
    ln_kernel<<<T_, 256, 0, stream>>>(x, ln2_g + l * D_, ln2_b + l * D_, h);
    gemm_mfma<false, false><<<dim3(T_ / 128, 16), 256, 0, stream>>>(h, p1l, pw1_b + l * 2048, nullptr, y, T_, 2048, D_);
    glu_kernel<<<T_ * INNER_ / 4 / 256, 256, 0, stream>>>(y, glu);
    dwconv_kernel<<<B_ * (N_ / TN_) * 4, 256, 0, stream>>>(glu, dwl, dw_b + l * INNER_, conv);
    // x = x + dw @ pw2^T + b
    gemm_mfma<true, false><<<dim3(T_ / 128, 4), 256, 0, stream>>>(conv, p2l, pw2_b + l * D_, x, x, T_, D_, INNER_);
  }

  {
    int n4 = T_ * D_ / 4;
    copy_kernel<<<(n4 + 255) / 256, 256, 0, stream>>>((const float4*)x, (float4*)d_out, n4);
  }
}

// Round 3
// 2938.882 us; speedup vs baseline: 3.1686x; 1.4809x over previous
//
#include <hip/hip_runtime.h>

// PCmer forward: bf16-MFMA everywhere (GEMMs + FAVOR attention einsums).
// L=6, B=4, N=2048, D=512, H=8, DH=64, ID=512, M=266, INNER=1024, K=31.

#define L_LAYERS 6
#define B_ 4
#define N_ 2048
#define D_ 512
#define H_ 8
#define DH_ 64
#define M_ 266
#define INNER_ 1024
#define T_ 8192            // B*N tokens
#define ROWS_ 65536        // B*N*H rows for phi
#define PS_ 320            // padded row stride for qp/kp (zeros in [266,320))

typedef __attribute__((ext_vector_type(8))) short short8;
typedef __attribute__((ext_vector_type(4))) float floatx4;

__device__ __forceinline__ ushort f2bf(float f) {
  union { float f; uint u; } v; v.f = f;
  uint r = v.u + 0x7fffu + ((v.u >> 16) & 1u);
  return (ushort)(r >> 16);
}
__device__ __forceinline__ float bf2f(ushort u) {
  union { uint u; float f; } v; v.u = ((uint)u) << 16;
  return v.f;
}

__device__ __forceinline__ float wave_sum(float v) {
#pragma unroll
  for (int m = 1; m < 64; m <<= 1) v += __shfl_xor(v, m);
  return v;
}
__device__ __forceinline__ float wave_max(float v) {
#pragma unroll
  for (int m = 1; m < 64; m <<= 1) v = fmaxf(v, __shfl_xor(v, m));
  return v;
}

// ---------------- copy / convert ----------------
__global__ void copy_kernel(const float4* __restrict__ in, float4* __restrict__ out, int n4) {
  int i = blockIdx.x * 256 + threadIdx.x;
  if (i < n4) out[i] = in[i];
}
__global__ void f2bf4_kernel(const float4* __restrict__ in, ushort* __restrict__ out, int n4) {
  int i = blockIdx.x * 256 + threadIdx.x;
  if (i < n4) {
    float4 v = in[i];
    ushort4 r;
    r.x = f2bf(v.x); r.y = f2bf(v.y); r.z = f2bf(v.z); r.w = f2bf(v.w);
    *(ushort4*)(out + (size_t)i * 4) = r;
  }
}

// ---------------- layernorm (block per token, D=512), bf16 out ----------------
__global__ __launch_bounds__(256) void ln_kernel(const float* __restrict__ x,
                                                 const float* __restrict__ g,
                                                 const float* __restrict__ b,
                                                 ushort* __restrict__ out) {
  const int t = blockIdx.x;
  const int tid = threadIdx.x;
  const float* row = x + (size_t)t * D_;
  float v0 = row[tid], v1 = row[tid + 256];
  float s1 = v0 + v1;
  float s2 = v0 * v0 + v1 * v1;
  s1 = wave_sum(s1);
  s2 = wave_sum(s2);
  __shared__ float sh1[4], sh2[4];
  int w = tid >> 6;
  if ((tid & 63) == 0) { sh1[w] = s1; sh2[w] = s2; }
  __syncthreads();
  s1 = sh1[0] + sh1[1] + sh1[2] + sh1[3];
  s2 = sh2[0] + sh2[1] + sh2[2] + sh2[3];
  float mu = s1 * (1.f / D_);
  float var = s2 * (1.f / D_) - mu * mu;
  float rs = rsqrtf(var + 1e-5f);
  out[(size_t)t * D_ + tid]       = f2bf((v0 - mu) * rs * g[tid] + b[tid]);
  out[(size_t)t * D_ + tid + 256] = f2bf((v1 - mu) * rs * g[tid + 256] + b[tid + 256]);
}

// ---------------- bf16 MFMA GEMM: C[t][n] = sum_k A[t][k]*W[n][k] + bias (+res) --------------
// 128x128 tile, BK=32, 4 waves. T%128==0, K%32==0. Cols: valid < Nn, zero-filled to < czero.
template <bool HAS_RES, bool OUT_BF16>
__global__ __launch_bounds__(256) void gemm_mfma(const ushort* __restrict__ A,
                                                 const ushort* __restrict__ W,
                                                 const float* __restrict__ bias,
                                                 const float* __restrict__ res,
                                                 void* __restrict__ Cout,
                                                 int T, int Nn, int K, int ldc, int czero) {
  __shared__ ushort As[128][40];
  __shared__ ushort Bs[128][40];
  const int tid = threadIdx.x;
  const int row0 = blockIdx.x * 128, col0 = blockIdx.y * 128;
  const int srow = tid >> 1;
  const int skh = (tid & 1) << 4;
  const ushort* gA = A + (size_t)(row0 + srow) * K + skh;
  const int wrow = col0 + srow;
  const ushort* gW = W + (size_t)wrow * K + skh;
  const bool wok = wrow < Nn;
  const int w = tid >> 6;
  const int lane = tid & 63;
  const int m16 = lane & 15;
  const int quad = lane >> 4;
  const int awr = (w >> 1) * 64;
  const int bwc = (w & 1) * 64;
  floatx4 acc[4][4] = {};
  const uint4 zz = make_uint4(0, 0, 0, 0);
  for (int k0 = 0; k0 < K; k0 += 32) {
    uint4 a0 = *(const uint4*)(gA + k0);
    uint4 a1 = *(const uint4*)(gA + k0 + 8);
    uint4 w0 = wok ? *(const uint4*)(gW + k0) : zz;
    uint4 w1 = wok ? *(const uint4*)(gW + k0 + 8) : zz;
    __syncthreads();
    *(uint4*)&As[srow][skh] = a0;
    *(uint4*)&As[srow][skh + 8] = a1;
    *(uint4*)&Bs[srow][skh] = w0;
    *(uint4*)&Bs[srow][skh + 8] = w1;
    __syncthreads();
    short8 af[4], bfr[4];
#pragma unroll
    for (int i = 0; i < 4; i++) af[i] = *(const short8*)&As[awr + i * 16 + m16][quad * 8];
#pragma unroll
    for (int j = 0; j < 4; j++) bfr[j] = *(const short8*)&Bs[bwc + j * 16 + m16][quad * 8];
#pragma unroll
    for (int i = 0; i < 4; i++)
#pragma unroll
      for (int j = 0; j < 4; j++)
        acc[i][j] = __builtin_amdgcn_mfma_f32_16x16x32_bf16(af[i], bfr[j], acc[i][j], 0, 0, 0);
  }
#pragma unroll
  for (int i = 0; i < 4; i++) {
    const int r0 = row0 + awr + i * 16 + quad * 4;
#pragma unroll
    for (int j = 0; j < 4; j++) {
      const int c = col0 + bwc + j * 16 + m16;
      if (c < czero) {
        const bool valid = c < Nn;
        const float base = (valid && bias) ? bias[c] : 0.f;
#pragma unroll
        for (int r = 0; r < 4; r++) {
          float vv = valid ? acc[i][j][r] + base : 0.f;
          if (HAS_RES) vv += res[(size_t)(r0 + r) * ldc + c];
          if (OUT_BF16) ((ushort*)Cout)[(size_t)(r0 + r) * ldc + c] = f2bf(vv);
          else          ((float*)Cout)[(size_t)(r0 + r) * ldc + c] = vv;
        }
      }
    }
  }
}

// ---------------- phi epilogue on bf16 p (stride PS_), wave per row ----------------
__global__ __launch_bounds__(256) void phi_epilogue(ushort* __restrict__ p,
                                                    const ushort* __restrict__ data,
                                                    int is_query) {
  const int t = blockIdx.x * 4 + (threadIdx.x >> 6);
  const int lane = threadIdx.x & 63;
  const float dn = 0.35355339059327373f;      // 64^-0.25
  const float ratio = 0.06131393394849658f;   // 266^-0.5
  float d = bf2f(data[(size_t)t * DH_ + lane]);
  float diag = 0.0625f * wave_sum(d * d);     // 0.5*dn^2
  ushort* row = p + (size_t)t * PS_;
  float vals[5];
  float mx = -1e30f;
#pragma unroll
  for (int i = 0; i < 5; i++) {
    int m = lane + (i << 6);
    float vv = (m < M_) ? dn * bf2f(row[m]) : -1e30f;
    vals[i] = vv;
    mx = fmaxf(mx, vv);
  }
  if (is_query) {
    mx = wave_max(mx);
#pragma unroll
    for (int i = 0; i < 5; i++) {
      int m = lane + (i << 6);
      if (m < M_) row[m] = f2bf(ratio * (expf(vals[i] - diag - mx) + 1e-4f));
    }
  } else {
#pragma unroll
    for (int i = 0; i < 5; i++) {
      int m = lane + (i << 6);
      if (m < M_) row[m] = f2bf(ratio * expf(vals[i] - diag + 1e-4f));
    }
  }
}

// ---------------- ksum[bh][m] = sum_n kp[b,n,h,m] ----------------
__global__ __launch_bounds__(256) void ksum_kernel(const ushort* __restrict__ kp,
                                                   float* __restrict__ ksum) {
  const int bh = blockIdx.x, mt = blockIdx.y, b = bh >> 3, h = bh & 7;
  const int ml = threadIdx.x & 63;
  const int ng = threadIdx.x >> 6;
  const int m = mt * 64 + ml;
  float s = 0.f;
  for (int n = ng; n < N_; n += 4)
    s += bf2f(kp[((size_t)((b * N_ + n) * H_ + h)) * PS_ + m]);
  __shared__ float sh[4][64];
  sh[ng][ml] = s;
  __syncthreads();
  if (threadIdx.x < 64)
    ksum[(size_t)bh * PS_ + mt * 64 + threadIdx.x] =
        sh[0][threadIdx.x] + sh[1][threadIdx.x] + sh[2][threadIdx.x] + sh[3][threadIdx.x];
}

// ---------------- ctx partials: MFMA over n-chunk of 256 ----------------
// grid (bh=32, mt=5, ns=8). part[bh][ns][mt][64m][64e] fp32.
__global__ __launch_bounds__(256) void ctx_mfma(const ushort* __restrict__ kp,
                                                const ushort* __restrict__ v,
                                                float* __restrict__ part) {
  __shared__ ushort kps[64][40];   // [m][n-chunk32], XOR-group swizzled
  __shared__ ushort vsT[64][40];   // [e][n-chunk32], XOR-group swizzled
  const int bh = blockIdx.x, mt = blockIdx.y, ns = blockIdx.z;
  const int b = bh >> 3, h = bh & 7;
  const int m0 = mt * 64;
  const int tid = threadIdx.x;
  const int w = tid >> 6, lane = tid & 63, l16 = lane & 15, quad = lane >> 4;
  const int nn = tid >> 3;       // 0..31
  const int a8 = tid & 7;        // row octet
  const int gn = nn >> 3, jn = nn & 7;
  const int pc = ((gn ^ (a8 & 3)) << 3) | jn;
  floatx4 acc[4] = {};
  for (int nstep = 0; nstep < 8; nstep++) {
    const int n0 = ns * 256 + nstep * 32;
    const size_t trow = (size_t)((b * N_ + n0 + nn) * H_ + h);
    uint4 kv = *(const uint4*)(kp + trow * PS_ + m0 + a8 * 8);
    uint4 vv = *(const uint4*)(v + ((size_t)(b * N_ + n0 + nn)) * 512 + h * 64 + a8 * 8);
    __syncthreads();
    const ushort* ke = (const ushort*)&kv;
    const ushort* ve = (const ushort*)&vv;
#pragma unroll
    for (int j = 0; j < 8; j++) kps[a8 * 8 + j][pc] = ke[j];
#pragma unroll
    for (int j = 0; j < 8; j++) vsT[a8 * 8 + j][pc] = ve[j];
    __syncthreads();
    const int am = w * 16 + l16;
    const int apg = quad ^ ((am >> 3) & 3);
    short8 af = *(const short8*)&kps[am][apg * 8];
#pragma unroll
    for (int et = 0; et < 4; et++) {
      const int be = et * 16 + l16;
      const int bpg = quad ^ ((be >> 3) & 3);
      short8 bf = *(const short8*)&vsT[be][bpg * 8];
      acc[et] = __builtin_amdgcn_mfma_f32_16x16x32_bf16(af, bf, acc[et], 0, 0, 0);
    }
  }
  float* pb = part + ((size_t)(bh * 8 + ns) * 5 + mt) * 4096;
#pragma unroll
  for (int et = 0; et < 4; et++)
#pragma unroll
    for (int r = 0; r < 4; r++)
      pb[(w * 16 + quad * 4 + r) * 64 + et * 16 + l16] = acc[et][r];
}

// ---------------- reduce partials -> ctxb bf16 [bh][288][64] (m>=266 are zeros) -------------
__global__ __launch_bounds__(256) void ctx_reduce(const float* __restrict__ part,
                                                  ushort* __restrict__ ctxb) {
  const int bh = blockIdx.x, mt = blockIdx.y;
  const int tid = threadIdx.x;
  for (int idx = tid; idx < 4096; idx += 256) {
    float s = 0.f;
#pragma unroll
    for (int ns = 0; ns < 8; ns++)
      s += part[((size_t)(bh * 8 + ns) * 5 + mt) * 4096 + idx];
    int m = mt * 64 + (idx >> 6);
    if (m < 288) ctxb[((size_t)bh * 288 + m) * 64 + (idx & 63)] = f2bf(s);
  }
}

// ---------------- d_inv (wave per row), bf16 qp ----------------
__global__ __launch_bounds__(256) void dinv_kernel(const ushort* __restrict__ qp,
                                                   const float* __restrict__ ksum,
                                                   float* __restrict__ dinv) {
  const int t = blockIdx.x * 4 + (threadIdx.x >> 6);
  const int lane = threadIdx.x & 63;
  const int h = t & 7;
  const int b = t >> 14;
  const ushort* row = qp + (size_t)t * PS_;
  const float* kr = ksum + (size_t)(b * H_ + h) * PS_;
  float acc = 0.f;
#pragma unroll
  for (int i = 0; i < 5; i++) {
    int m = lane + (i << 6);
    acc += bf2f(row[m]) * kr[m];   // pads are zero on both sides
  }
  acc = wave_sum(acc);
  if (lane == 0) dinv[t] = 1.f / (acc + 1e-8f);
}

// ---------------- attention out: MFMA o[n][e] = dinv * sum_m qp[n][m]*ctxb[m][e] -------------
// grid (bh=32, nt=32). K = 288 (zero-padded).
__global__ __launch_bounds__(256) void attn_out_mfma(const ushort* __restrict__ qp,
                                                     const ushort* __restrict__ ctxb,
                                                     const float* __restrict__ dinv,
                                                     ushort* __restrict__ o) {
  __shared__ ushort qs[64][40];   // [n][m-chunk32], plain
  __shared__ ushort cs[64][40];   // [e][m-chunk32], XOR-group swizzled
  const int bh = blockIdx.x, b = bh >> 3, h = bh & 7;
  const int n0 = blockIdx.y * 64;
  const int tid = threadIdx.x;
  const int w = tid >> 6, lane = tid & 63, l16 = lane & 15, quad = lane >> 4;
  const int qn = tid >> 2, qms = (tid & 3) * 8;
  const int cm = tid >> 3, ca8 = tid & 7;
  const int gm = cm >> 3, jm = cm & 7;
  const int pcc = ((gm ^ (ca8 & 3)) << 3) | jm;
  floatx4 acc[4] = {};
  for (int m0 = 0; m0 < 288; m0 += 32) {
    uint4 qv = *(const uint4*)(qp + ((size_t)((b * N_ + n0 + qn) * H_ + h)) * PS_ + m0 + qms);
    uint4 cv = *(const uint4*)(ctxb + ((size_t)bh * 288 + m0 + cm) * 64 + ca8 * 8);
    __syncthreads();
    *(uint4*)&qs[qn][qms] = qv;
    const ushort* ce = (const ushort*)&cv;
#pragma unroll
    for (int j = 0; j < 8; j++) cs[ca8 * 8 + j][pcc] = ce[j];
    __syncthreads();
    short8 af = *(const short8*)&qs[w * 16 + l16][quad * 8];
#pragma unroll
    for (int et = 0; et < 4; et++) {
      const int be = et * 16 + l16;
      const int bpg = quad ^ ((be >> 3) & 3);
      short8 bf = *(const short8*)&cs[be][bpg * 8];
      acc[et] = __builtin_amdgcn_mfma_f32_16x16x32_bf16(af, bf, acc[et], 0, 0, 0);
    }
  }
#pragma unroll
  for (int r = 0; r < 4; r++) {
    const int n = n0 + w * 16 + quad * 4 + r;
    const size_t t = (size_t)(b * N_ + n) * H_ + h;
    const float di = dinv[t];
#pragma unroll
    for (int et = 0; et < 4; et++)
      o[((size_t)(b * N_ + n)) * 512 + h * 64 + et * 16 + l16] = f2bf(acc[et][r] * di);
  }
}

// ---------------- GLU bf16: out[t,c] = a * sigmoid(g) ----------------
__global__ void glu_kernel(const ushort* __restrict__ y, ushort* __restrict__ out) {
  int i = blockIdx.x * 256 + threadIdx.x;  // over T*1024/8
  int t = i >> 7, c8 = (i & 127) * 8;
  uint4 av = *(const uint4*)(y + (size_t)t * 2048 + c8);
  uint4 gv = *(const uint4*)(y + (size_t)t * 2048 + 1024 + c8);
  const ushort* ae = (const ushort*)&av;
  const ushort* ge = (const ushort*)&gv;
  ushort r[8];
#pragma unroll
  for (int j = 0; j < 8; j++) {
    float fa = bf2f(ae[j]), fg = bf2f(ge[j]);
    r[j] = f2bf(fa / (1.f + expf(-fg)));
  }
  *(uint4*)(out + (size_t)i * 8) = *(uint4*)r;
}

// ---------------- depthwise conv K=31, pad 15, + bias + silu; bf16 in/out ----------------
#define TN_ 16
__global__ __launch_bounds__(256) void dwconv_kernel(const ushort* __restrict__ x,
                                                     const float* __restrict__ w,
                                                     const float* __restrict__ bias,
                                                     ushort* __restrict__ out) {
  const int bid = blockIdx.x;
  const int cb = bid & 3;
  const int nb = (bid >> 2) & 127;
  const int b  = bid >> 9;
  const int c = cb * 256 + threadIdx.x;
  const int n0 = nb * TN_;
  float win[TN_ + 30];
#pragma unroll
  for (int i = 0; i < TN_ + 30; i++) {
    int nn = n0 + i - 15;
    win[i] = (nn >= 0 && nn < N_) ? bf2f(x[(size_t)(b * N_ + nn) * INNER_ + c]) : 0.f;
  }
  float wc[31];
#pragma unroll
  for (int kk = 0; kk < 31; kk++) wc[kk] = w[c * 31 + kk];
  const float bsv = bias[c];
#pragma unroll
  for (int j = 0; j < TN_; j++) {
    float acc = bsv;
#pragma unroll
    for (int kk = 0; kk < 31; kk++) acc += win[j + kk] * wc[kk];
    acc = acc / (1.f + expf(-acc));
    out[(size_t)(b * N_ + n0 + j) * INNER_ + c] = f2bf(acc);
  }
}

// ---------------- host ----------------
extern "C" void kernel_launch(void* const* d_in, const int* in_sizes, int n_in,
                              void* d_out, int out_size, void* d_ws, size_t ws_size,
                              hipStream_t stream) {
  const float* in_x  = (const float*)d_in[0];
  const float* ln1_g = (const float*)d_in[1];
  const float* ln1_b = (const float*)d_in[2];
  const float* wq    = (const float*)d_in[3];
  const float* bq    = (const float*)d_in[4];
  const float* wk    = (const float*)d_in[5];
  const float* bk    = (const float*)d_in[6];
  const float* wv    = (const float*)d_in[7];
  const float* bv    = (const float*)d_in[8];
  const float* wo    = (const float*)d_in[9];
  const float* bo    = (const float*)d_in[10];
  const float* proj  = (const float*)d_in[11];
  const float* ln2_g = (const float*)d_in[12];
  const float* ln2_b = (const float*)d_in[13];
  const float* pw1_w = (const float*)d_in[14];
  const float* pw1_b = (const float*)d_in[15];
  const float* dw_w  = (const float*)d_in[16];
  const float* dw_b  = (const float*)d_in[17];
  const float* pw2_w = (const float*)d_in[18];
  const float* pw2_b = (const float*)d_in[19];

  char* cur = (char*)d_ws;
  auto alloc = [&](size_t bytes) { char* p = cur; cur += (bytes + 255) & ~(size_t)255; return p; };
  float*  x    = (float*)alloc((size_t)T_ * D_ * 4);
  ushort* p    = (ushort*)alloc((size_t)ROWS_ * PS_ * 2);      // qp/kp; glu+conv alias
  float*  part = (float*)alloc((size_t)32 * 8 * 5 * 4096 * 4); // ctx partials, 21 MB
  ushort* ctxb = (ushort*)alloc((size_t)32 * 288 * 64 * 2);
  float*  ksum = (float*)alloc((size_t)32 * PS_ * 4);
  float*  dinv = (float*)alloc((size_t)ROWS_ * 4);
  ushort* y    = (ushort*)alloc((size_t)T_ * 2048 * 2);
  ushort* h    = (ushort*)alloc((size_t)T_ * D_ * 2);
  ushort* q    = (ushort*)alloc((size_t)T_ * D_ * 2);
  ushort* k    = (ushort*)alloc((size_t)T_ * D_ * 2);
  ushort* v    = (ushort*)alloc((size_t)T_ * D_ * 2);
  ushort* obuf = (ushort*)alloc((size_t)T_ * D_ * 2);
  ushort* wq_b = (ushort*)alloc((size_t)L_LAYERS * D_ * D_ * 2);
  ushort* wk_b = (ushort*)alloc((size_t)L_LAYERS * D_ * D_ * 2);
  ushort* wv_b = (ushort*)alloc((size_t)L_LAYERS * D_ * D_ * 2);
  ushort* wo_b = (ushort*)alloc((size_t)L_LAYERS * D_ * D_ * 2);
  ushort* pj_b = (ushort*)alloc((size_t)L_LAYERS * M_ * DH_ * 2);
  ushort* p1_b = (ushort*)alloc((size_t)L_LAYERS * 2048 * D_ * 2);
  ushort* p2_b = (ushort*)alloc((size_t)L_LAYERS * D_ * INNER_ * 2);
  // glu (bf16 T*1024) and conv (bf16 T*1024) alias the p region (dead between attention phases)
  ushort* glu  = p;
  ushort* conv = p + (size_t)T_ * INNER_;

  auto conv_w = [&](const float* src, ushort* dst, size_t n) {
    int n4 = (int)(n / 4);
    f2bf4_kernel<<<(n4 + 255) / 256, 256, 0, stream>>>((const float4*)src, dst, n4);
  };
  conv_w(wq, wq_b, (size_t)L_LAYERS * D_ * D_);
  conv_w(wk, wk_b, (size_t)L_LAYERS * D_ * D_);
  conv_w(wv, wv_b, (size_t)L_LAYERS * D_ * D_);
  conv_w(wo, wo_b, (size_t)L_LAYERS * D_ * D_);
  conv_w(proj, pj_b, (size_t)L_LAYERS * M_ * DH_);
  conv_w(pw1_w, p1_b, (size_t)L_LAYERS * 2048 * D_);
  conv_w(pw2_w, p2_b, (size_t)L_LAYERS * D_ * INNER_);

  {
    int n4 = T_ * D_ / 4;
    copy_kernel<<<(n4 + 255) / 256, 256, 0, stream>>>((const float4*)in_x, (float4*)x, n4);
  }

  for (int l = 0; l < L_LAYERS; l++) {
    const ushort* wql = wq_b + (size_t)l * D_ * D_;
    const ushort* wkl = wk_b + (size_t)l * D_ * D_;
    const ushort* wvl = wv_b + (size_t)l * D_ * D_;
    const ushort* wol = wo_b + (size_t)l * D_ * D_;
    const ushort* pjl = pj_b + (size_t)l * M_ * DH_;
    const ushort* p1l = p1_b + (size_t)l * 2048 * D_;
    const ushort* p2l = p2_b + (size_t)l * D_ * INNER_;
    const float*  dwl = dw_w + (size_t)l * INNER_ * 31;

    ln_kernel<<<T_, 256, 0, stream>>>(x, ln1_g + l * D_, ln1_b + l * D_, h);
    gemm_mfma<false, true><<<dim3(T_ / 128, 4), 256, 0, stream>>>(h, wql, bq + l * D_, nullptr, q, T_, D_, D_, D_, D_);
    gemm_mfma<false, true><<<dim3(T_ / 128, 4), 256, 0, stream>>>(h, wkl, bk + l * D_, nullptr, k, T_, D_, D_, D_, D_);
    gemm_mfma<false, true><<<dim3(T_ / 128, 4), 256, 0, stream>>>(h, wvl, bv + l * D_, nullptr, v, T_, D_, D_, D_, D_);
    // kp features (bf16, stride 320, zero-padded cols >= 266)
    gemm_mfma<false, true><<<dim3(ROWS_ / 128, 3), 256, 0, stream>>>(k, pjl, nullptr, nullptr, p, ROWS_, M_, DH_, PS_, PS_);
    phi_epilogue<<<ROWS_ / 4, 256, 0, stream>>>(p, k, 0);
    ksum_kernel<<<dim3(32, 5), 256, 0, stream>>>(p, ksum);
    ctx_mfma<<<dim3(32, 5, 8), 256, 0, stream>>>(p, v, part);
    ctx_reduce<<<dim3(32, 5), 256, 0, stream>>>(part, ctxb);
    // qp features
    gemm_mfma<false, true><<<dim3(ROWS_ / 128, 3), 256, 0, stream>>>(q, pjl, nullptr, nullptr, p, ROWS_, M_, DH_, PS_, PS_);
    phi_epilogue<<<ROWS_ / 4, 256, 0, stream>>>(p, q, 1);
    dinv_kernel<<<ROWS_ / 4, 256, 0, stream>>>(p, ksum, dinv);
    attn_out_mfma<<<dim3(32, 32), 256, 0, stream>>>(p, ctxb, dinv, obuf);
    // x = x + o @ wo^T + bo
    gemm_mfma<true, false><<<dim3(T_ / 128, 4), 256, 0, stream>>>(obuf, wol, bo + l * D_, x, x, T_, D_, D_, D_, D_);
    // FF branch
    ln_kernel<<<T_, 256, 0, stream>>>(x, ln2_g + l * D_, ln2_b + l * D_, h);
    gemm_mfma<false, true><<<dim3(T_ / 128, 16), 256, 0, stream>>>(h, p1l, pw1_b + l * 2048, nullptr, y, T_, 2048, D_, 2048, 2048);
    glu_kernel<<<T_ * INNER_ / 8 / 256, 256, 0, stream>>>(y, glu);
    dwconv_kernel<<<B_ * (N_ / TN_) * 4, 256, 0, stream>>>(glu, dwl, dw_b + l * INNER_, conv);
    gemm_mfma<true, false><<<dim3(T_ / 128, 4), 256, 0, stream>>>(conv, p2l, pw2_b + l * D_, x, x, T_, D_, INNER_, D_, D_);
  }

  {
    int n4 = T_ * D_ / 4;
    copy_kernel<<<(n4 + 255) / 256, 256, 0, stream>>>((const float4*)x, (float4*)d_out, n4);
  }
}

// Round 4
// 2076.591 us; speedup vs baseline: 4.4844x; 1.4152x over previous
//
#include <hip/hip_runtime.h>

// PCmer forward: bf16-MFMA everywhere; ksum fused into ctx, dinv fused into attn_out.
// L=6, B=4, N=2048, D=512, H=8, DH=64, ID=512, M=266, INNER=1024, K=31.

#define L_LAYERS 6
#define B_ 4
#define N_ 2048
#define D_ 512
#define H_ 8
#define DH_ 64
#define M_ 266
#define INNER_ 1024
#define T_ 8192            // B*N tokens
#define ROWS_ 65536        // B*N*H rows for phi
#define PS_ 320            // padded row stride for qp/kp (zeros in [266,320))

typedef __attribute__((ext_vector_type(8))) short short8;
typedef __attribute__((ext_vector_type(4))) float floatx4;

__device__ __forceinline__ ushort f2bf(float f) {
  union { float f; uint u; } v; v.f = f;
  uint r = v.u + 0x7fffu + ((v.u >> 16) & 1u);
  return (ushort)(r >> 16);
}
__device__ __forceinline__ float bf2f(ushort u) {
  union { uint u; float f; } v; v.u = ((uint)u) << 16;
  return v.f;
}

__device__ __forceinline__ float wave_sum(float v) {
#pragma unroll
  for (int m = 1; m < 64; m <<= 1) v += __shfl_xor(v, m);
  return v;
}
__device__ __forceinline__ float wave_max(float v) {
#pragma unroll
  for (int m = 1; m < 64; m <<= 1) v = fmaxf(v, __shfl_xor(v, m));
  return v;
}

// ---------------- convert ----------------
__global__ void f2bf4_kernel(const float4* __restrict__ in, ushort* __restrict__ out, int n4) {
  int i = blockIdx.x * 256 + threadIdx.x;
  if (i < n4) {
    float4 v = in[i];
    ushort4 r;
    r.x = f2bf(v.x); r.y = f2bf(v.y); r.z = f2bf(v.z); r.w = f2bf(v.w);
    *(ushort4*)(out + (size_t)i * 4) = r;
  }
}

// ---------------- layernorm (block per token, D=512), bf16 out ----------------
__global__ __launch_bounds__(256) void ln_kernel(const float* __restrict__ x,
                                                 const float* __restrict__ g,
                                                 const float* __restrict__ b,
                                                 ushort* __restrict__ out) {
  const int t = blockIdx.x;
  const int tid = threadIdx.x;
  const float* row = x + (size_t)t * D_;
  float v0 = row[tid], v1 = row[tid + 256];
  float s1 = v0 + v1;
  float s2 = v0 * v0 + v1 * v1;
  s1 = wave_sum(s1);
  s2 = wave_sum(s2);
  __shared__ float sh1[4], sh2[4];
  int w = tid >> 6;
  if ((tid & 63) == 0) { sh1[w] = s1; sh2[w] = s2; }
  __syncthreads();
  s1 = sh1[0] + sh1[1] + sh1[2] + sh1[3];
  s2 = sh2[0] + sh2[1] + sh2[2] + sh2[3];
  float mu = s1 * (1.f / D_);
  float var = s2 * (1.f / D_) - mu * mu;
  float rs = rsqrtf(var + 1e-5f);
  out[(size_t)t * D_ + tid]       = f2bf((v0 - mu) * rs * g[tid] + b[tid]);
  out[(size_t)t * D_ + tid + 256] = f2bf((v1 - mu) * rs * g[tid + 256] + b[tid + 256]);
}

// ---------------- bf16 MFMA GEMM: C[t][n] = sum_k A[t][k]*W[n][k] + bias (+res) --------------
// 128x128 tile, BK=32, 4 waves. T%128==0, K%32==0. Cols: valid < Nn, zero-filled to < czero.
template <bool HAS_RES, bool OUT_BF16>
__global__ __launch_bounds__(256) void gemm_mfma(const ushort* __restrict__ A,
                                                 const ushort* __restrict__ W,
                                                 const float* __restrict__ bias,
                                                 const float* __restrict__ res,
                                                 void* __restrict__ Cout,
                                                 int T, int Nn, int K, int ldc, int czero) {
  __shared__ ushort As[128][40];
  __shared__ ushort Bs[128][40];
  const int tid = threadIdx.x;
  const int row0 = blockIdx.x * 128, col0 = blockIdx.y * 128;
  const int srow = tid >> 1;
  const int skh = (tid & 1) << 4;
  const ushort* gA = A + (size_t)(row0 + srow) * K + skh;
  const int wrow = col0 + srow;
  const ushort* gW = W + (size_t)wrow * K + skh;
  const bool wok = wrow < Nn;
  const int w = tid >> 6;
  const int lane = tid & 63;
  const int m16 = lane & 15;
  const int quad = lane >> 4;
  const int awr = (w >> 1) * 64;
  const int bwc = (w & 1) * 64;
  floatx4 acc[4][4] = {};
  const uint4 zz = make_uint4(0, 0, 0, 0);
  for (int k0 = 0; k0 < K; k0 += 32) {
    uint4 a0 = *(const uint4*)(gA + k0);
    uint4 a1 = *(const uint4*)(gA + k0 + 8);
    uint4 w0 = wok ? *(const uint4*)(gW + k0) : zz;
    uint4 w1 = wok ? *(const uint4*)(gW + k0 + 8) : zz;
    __syncthreads();
    *(uint4*)&As[srow][skh] = a0;
    *(uint4*)&As[srow][skh + 8] = a1;
    *(uint4*)&Bs[srow][skh] = w0;
    *(uint4*)&Bs[srow][skh + 8] = w1;
    __syncthreads();
    short8 af[4], bfr[4];
#pragma unroll
    for (int i = 0; i < 4; i++) af[i] = *(const short8*)&As[awr + i * 16 + m16][quad * 8];
#pragma unroll
    for (int j = 0; j < 4; j++) bfr[j] = *(const short8*)&Bs[bwc + j * 16 + m16][quad * 8];
#pragma unroll
    for (int i = 0; i < 4; i++)
#pragma unroll
      for (int j = 0; j < 4; j++)
        acc[i][j] = __builtin_amdgcn_mfma_f32_16x16x32_bf16(af[i], bfr[j], acc[i][j], 0, 0, 0);
  }
#pragma unroll
  for (int i = 0; i < 4; i++) {
    const int r0 = row0 + awr + i * 16 + quad * 4;
#pragma unroll
    for (int j = 0; j < 4; j++) {
      const int c = col0 + bwc + j * 16 + m16;
      if (c < czero) {
        const bool valid = c < Nn;
        const float base = (valid && bias) ? bias[c] : 0.f;
#pragma unroll
        for (int r = 0; r < 4; r++) {
          float vv = valid ? acc[i][j][r] + base : 0.f;
          if (HAS_RES) vv += res[(size_t)(r0 + r) * ldc + c];
          if (OUT_BF16) ((ushort*)Cout)[(size_t)(r0 + r) * ldc + c] = f2bf(vv);
          else          ((float*)Cout)[(size_t)(r0 + r) * ldc + c] = vv;
        }
      }
    }
  }
}

// ---------------- phi epilogue on bf16 p (stride PS_), wave per row ----------------
__global__ __launch_bounds__(256) void phi_epilogue(ushort* __restrict__ p,
                                                    const ushort* __restrict__ data,
                                                    int is_query) {
  const int t = blockIdx.x * 4 + (threadIdx.x >> 6);
  const int lane = threadIdx.x & 63;
  const float dn = 0.35355339059327373f;      // 64^-0.25
  const float ratio = 0.06131393394849658f;   // 266^-0.5
  float d = bf2f(data[(size_t)t * DH_ + lane]);
  float diag = 0.0625f * wave_sum(d * d);     // 0.5*dn^2
  ushort* row = p + (size_t)t * PS_;
  float vals[5];
  float mx = -1e30f;
#pragma unroll
  for (int i = 0; i < 5; i++) {
    int m = lane + (i << 6);
    float vv = (m < M_) ? dn * bf2f(row[m]) : -1e30f;
    vals[i] = vv;
    mx = fmaxf(mx, vv);
  }
  if (is_query) {
    mx = wave_max(mx);
#pragma unroll
    for (int i = 0; i < 5; i++) {
      int m = lane + (i << 6);
      if (m < M_) row[m] = f2bf(ratio * (expf(vals[i] - diag - mx) + 1e-4f));
    }
  } else {
#pragma unroll
    for (int i = 0; i < 5; i++) {
      int m = lane + (i << 6);
      if (m < M_) row[m] = f2bf(ratio * expf(vals[i] - diag + 1e-4f));
    }
  }
}

// ---------------- ctx partials + ksum partials: MFMA over n-chunk of 256 ----------------
// grid (bh=32, mt=5, ns=8). part[bh][ns][mt][64m][64e] fp32; kpart[bh][ns][mt][64m].
__global__ __launch_bounds__(256) void ctx_mfma(const ushort* __restrict__ kp,
                                                const ushort* __restrict__ v,
                                                float* __restrict__ part,
                                                float* __restrict__ kpart) {
  __shared__ ushort kps[64][40];   // [m][n-chunk32], XOR-group swizzled
  __shared__ ushort vsT[64][40];   // [e][n-chunk32], XOR-group swizzled
  __shared__ float kshare[4][64];
  const int bh = blockIdx.x, mt = blockIdx.y, ns = blockIdx.z;
  const int b = bh >> 3, h = bh & 7;
  const int m0 = mt * 64;
  const int tid = threadIdx.x;
  const int w = tid >> 6, lane = tid & 63, l16 = lane & 15, quad = lane >> 4;
  const int nn = tid >> 3;       // 0..31
  const int a8 = tid & 7;        // row octet
  const int gn = nn >> 3, jn = nn & 7;
  const int pc = ((gn ^ (a8 & 3)) << 3) | jn;
  const int km = tid & 63, kg = tid >> 6;  // ksum mapping
  floatx4 acc[4] = {};
  float ksp = 0.f;
  for (int nstep = 0; nstep < 8; nstep++) {
    const int n0 = ns * 256 + nstep * 32;
    const size_t trow = (size_t)((b * N_ + n0 + nn) * H_ + h);
    uint4 kv = *(const uint4*)(kp + trow * PS_ + m0 + a8 * 8);
    uint4 vv = *(const uint4*)(v + ((size_t)(b * N_ + n0 + nn)) * 512 + h * 64 + a8 * 8);
    __syncthreads();
    const ushort* ke = (const ushort*)&kv;
    const ushort* ve = (const ushort*)&vv;
#pragma unroll
    for (int j = 0; j < 8; j++) kps[a8 * 8 + j][pc] = ke[j];
#pragma unroll
    for (int j = 0; j < 8; j++) vsT[a8 * 8 + j][pc] = ve[j];
    __syncthreads();
    const int am = w * 16 + l16;
    const int apg = quad ^ ((am >> 3) & 3);
    short8 af = *(const short8*)&kps[am][apg * 8];
#pragma unroll
    for (int et = 0; et < 4; et++) {
      const int be = et * 16 + l16;
      const int bpg = quad ^ ((be >> 3) & 3);
      short8 bf = *(const short8*)&vsT[be][bpg * 8];
      acc[et] = __builtin_amdgcn_mfma_f32_16x16x32_bf16(af, bf, acc[et], 0, 0, 0);
    }
    // ksum partial: sum 8 n-entries of row km (swizzle permutes n within row; sum invariant)
    {
      short8 kr = *(const short8*)&kps[km][kg * 8];
      const ushort* ku = (const ushort*)&kr;
#pragma unroll
      for (int j = 0; j < 8; j++) ksp += bf2f(ku[j]);
    }
  }
  float* pb = part + ((size_t)(bh * 8 + ns) * 5 + mt) * 4096;
#pragma unroll
  for (int et = 0; et < 4; et++)
#pragma unroll
    for (int r = 0; r < 4; r++)
      pb[(w * 16 + quad * 4 + r) * 64 + et * 16 + l16] = acc[et][r];
  kshare[kg][km] = ksp;
  __syncthreads();
  if (tid < 64)
    kpart[((size_t)(bh * 8 + ns) * 5 + mt) * 64 + tid] =
        kshare[0][tid] + kshare[1][tid] + kshare[2][tid] + kshare[3][tid];
}

// ---------------- reduce partials -> ctxb bf16 [bh][288][64] + ksum[bh][PS_] ----------------
__global__ __launch_bounds__(256) void ctx_reduce(const float* __restrict__ part,
                                                  const float* __restrict__ kpart,
                                                  ushort* __restrict__ ctxb,
                                                  float* __restrict__ ksum) {
  const int bh = blockIdx.x, mt = blockIdx.y;
  const int tid = threadIdx.x;
  for (int idx = tid; idx < 4096; idx += 256) {
    float s = 0.f;
#pragma unroll
    for (int ns = 0; ns < 8; ns++)
      s += part[((size_t)(bh * 8 + ns) * 5 + mt) * 4096 + idx];
    int m = mt * 64 + (idx >> 6);
    if (m < 288) ctxb[((size_t)bh * 288 + m) * 64 + (idx & 63)] = f2bf(s);
  }
  if (tid < 64) {
    float s = 0.f;
#pragma unroll
    for (int ns = 0; ns < 8; ns++)
      s += kpart[((size_t)(bh * 8 + ns) * 5 + mt) * 64 + tid];
    ksum[(size_t)bh * PS_ + mt * 64 + tid] = s;
  }
}

// ---------------- attention out (dinv fused): o = dinv * (qp @ ctxb) ----------------
// grid (bh=32, nt=32). K = 288 (zero-padded).
__global__ __launch_bounds__(256) void attn_out_mfma(const ushort* __restrict__ qp,
                                                     const ushort* __restrict__ ctxb,
                                                     const float* __restrict__ ksum,
                                                     ushort* __restrict__ o) {
  __shared__ ushort qs[64][40];   // [n][m-chunk32], plain
  __shared__ ushort cs[64][40];   // [e][m-chunk32], XOR-group swizzled
  __shared__ float ks_sh[PS_];
  __shared__ float dsh[64];
  const int bh = blockIdx.x, b = bh >> 3, h = bh & 7;
  const int n0 = blockIdx.y * 64;
  const int tid = threadIdx.x;
  const int w = tid >> 6, lane = tid & 63, l16 = lane & 15, quad = lane >> 4;
  const int qn = tid >> 2, qms = (tid & 3) * 8;
  const int cm = tid >> 3, ca8 = tid & 7;
  const int gm = cm >> 3, jm = cm & 7;
  const int pcc = ((gm ^ (ca8 & 3)) << 3) | jm;
  for (int i = tid; i < PS_; i += 256) ks_sh[i] = ksum[(size_t)bh * PS_ + i];
  floatx4 acc[4] = {};
  float dacc = 0.f;
  for (int m0 = 0; m0 < 288; m0 += 32) {
    uint4 qv = *(const uint4*)(qp + ((size_t)((b * N_ + n0 + qn) * H_ + h)) * PS_ + m0 + qms);
    uint4 cv = *(const uint4*)(ctxb + ((size_t)bh * 288 + m0 + cm) * 64 + ca8 * 8);
    __syncthreads();
    *(uint4*)&qs[qn][qms] = qv;
    const ushort* ce = (const ushort*)&cv;
#pragma unroll
    for (int j = 0; j < 8; j++) cs[ca8 * 8 + j][pcc] = ce[j];
    // dinv partial from the register copy of qp (ks_sh loaded before first barrier)
    const ushort* qe = (const ushort*)&qv;
#pragma unroll
    for (int j = 0; j < 8; j++) dacc += bf2f(qe[j]) * ks_sh[m0 + qms + j];
    __syncthreads();
    short8 af = *(const short8*)&qs[w * 16 + l16][quad * 8];
#pragma unroll
    for (int et = 0; et < 4; et++) {
      const int be = et * 16 + l16;
      const int bpg = quad ^ ((be >> 3) & 3);
      short8 bf = *(const short8*)&cs[be][bpg * 8];
      acc[et] = __builtin_amdgcn_mfma_f32_16x16x32_bf16(af, bf, acc[et], 0, 0, 0);
    }
  }
  // reduce dinv across the 4 consecutive lanes sharing row qn
  dacc += __shfl_xor(dacc, 1);
  dacc += __shfl_xor(dacc, 2);
  if ((tid & 3) == 0) dsh[qn] = 1.f / (dacc + 1e-8f);
  __syncthreads();
#pragma unroll
  for (int r = 0; r < 4; r++) {
    const int nl = w * 16 + quad * 4 + r;
    const int n = n0 + nl;
    const float di = dsh[nl];
#pragma unroll
    for (int et = 0; et < 4; et++)
      o[((size_t)(b * N_ + n)) * 512 + h * 64 + et * 16 + l16] = f2bf(acc[et][r] * di);
  }
}

// ---------------- GLU bf16: out[t,c] = a * sigmoid(g) ----------------
__global__ void glu_kernel(const ushort* __restrict__ y, ushort* __restrict__ out) {
  int i = blockIdx.x * 256 + threadIdx.x;  // over T*1024/8
  int t = i >> 7, c8 = (i & 127) * 8;
  uint4 av = *(const uint4*)(y + (size_t)t * 2048 + c8);
  uint4 gv = *(const uint4*)(y + (size_t)t * 2048 + 1024 + c8);
  const ushort* ae = (const ushort*)&av;
  const ushort* ge = (const ushort*)&gv;
  ushort r[8];
#pragma unroll
  for (int j = 0; j < 8; j++) {
    float fa = bf2f(ae[j]), fg = bf2f(ge[j]);
    r[j] = f2bf(fa / (1.f + expf(-fg)));
  }
  *(uint4*)(out + (size_t)i * 8) = *(uint4*)r;
}

// ---------------- depthwise conv K=31, pad 15, + bias + silu; bf16 in/out ----------------
#define TN_ 16
__global__ __launch_bounds__(256) void dwconv_kernel(const ushort* __restrict__ x,
                                                     const float* __restrict__ w,
                                                     const float* __restrict__ bias,
                                                     ushort* __restrict__ out) {
  const int bid = blockIdx.x;
  const int cb = bid & 3;
  const int nb = (bid >> 2) & 127;
  const int b  = bid >> 9;
  const int c = cb * 256 + threadIdx.x;
  const int n0 = nb * TN_;
  float win[TN_ + 30];
#pragma unroll
  for (int i = 0; i < TN_ + 30; i++) {
    int nn = n0 + i - 15;
    win[i] = (nn >= 0 && nn < N_) ? bf2f(x[(size_t)(b * N_ + nn) * INNER_ + c]) : 0.f;
  }
  float wc[31];
#pragma unroll
  for (int kk = 0; kk < 31; kk++) wc[kk] = w[c * 31 + kk];
  const float bsv = bias[c];
#pragma unroll
  for (int j = 0; j < TN_; j++) {
    float acc = bsv;
#pragma unroll
    for (int kk = 0; kk < 31; kk++) acc += win[j + kk] * wc[kk];
    acc = acc / (1.f + expf(-acc));
    out[(size_t)(b * N_ + n0 + j) * INNER_ + c] = f2bf(acc);
  }
}

// ---------------- host ----------------
extern "C" void kernel_launch(void* const* d_in, const int* in_sizes, int n_in,
                              void* d_out, int out_size, void* d_ws, size_t ws_size,
                              hipStream_t stream) {
  const float* in_x  = (const float*)d_in[0];
  const float* ln1_g = (const float*)d_in[1];
  const float* ln1_b = (const float*)d_in[2];
  const float* wq    = (const float*)d_in[3];
  const float* bq    = (const float*)d_in[4];
  const float* wk    = (const float*)d_in[5];
  const float* bk    = (const float*)d_in[6];
  const float* wv    = (const float*)d_in[7];
  const float* bv    = (const float*)d_in[8];
  const float* wo    = (const float*)d_in[9];
  const float* bo    = (const float*)d_in[10];
  const float* proj  = (const float*)d_in[11];
  const float* ln2_g = (const float*)d_in[12];
  const float* ln2_b = (const float*)d_in[13];
  const float* pw1_w = (const float*)d_in[14];
  const float* pw1_b = (const float*)d_in[15];
  const float* dw_w  = (const float*)d_in[16];
  const float* dw_b  = (const float*)d_in[17];
  const float* pw2_w = (const float*)d_in[18];
  const float* pw2_b = (const float*)d_in[19];

  char* cur = (char*)d_ws;
  auto alloc = [&](size_t bytes) { char* p = cur; cur += (bytes + 255) & ~(size_t)255; return p; };
  float*  x    = (float*)alloc((size_t)T_ * D_ * 4);
  ushort* p    = (ushort*)alloc((size_t)ROWS_ * PS_ * 2);      // qp/kp; glu+conv alias
  float*  part = (float*)alloc((size_t)32 * 8 * 5 * 4096 * 4); // ctx partials
  float*  kpart= (float*)alloc((size_t)32 * 8 * 5 * 64 * 4);   // ksum partials
  ushort* ctxb = (ushort*)alloc((size_t)32 * 288 * 64 * 2);
  float*  ksum = (float*)alloc((size_t)32 * PS_ * 4);
  ushort* y    = (ushort*)alloc((size_t)T_ * 2048 * 2);
  ushort* h    = (ushort*)alloc((size_t)T_ * D_ * 2);
  ushort* q    = (ushort*)alloc((size_t)T_ * D_ * 2);
  ushort* k    = (ushort*)alloc((size_t)T_ * D_ * 2);
  ushort* v    = (ushort*)alloc((size_t)T_ * D_ * 2);
  ushort* obuf = (ushort*)alloc((size_t)T_ * D_ * 2);
  ushort* wq_b = (ushort*)alloc((size_t)L_LAYERS * D_ * D_ * 2);
  ushort* wk_b = (ushort*)alloc((size_t)L_LAYERS * D_ * D_ * 2);
  ushort* wv_b = (ushort*)alloc((size_t)L_LAYERS * D_ * D_ * 2);
  ushort* wo_b = (ushort*)alloc((size_t)L_LAYERS * D_ * D_ * 2);
  ushort* pj_b = (ushort*)alloc((size_t)L_LAYERS * M_ * DH_ * 2);
  ushort* p1_b = (ushort*)alloc((size_t)L_LAYERS * 2048 * D_ * 2);
  ushort* p2_b = (ushort*)alloc((size_t)L_LAYERS * D_ * INNER_ * 2);
  ushort* glu  = p;
  ushort* conv = p + (size_t)T_ * INNER_;

  auto conv_w = [&](const float* src, ushort* dst, size_t n) {
    int n4 = (int)(n / 4);
    f2bf4_kernel<<<(n4 + 255) / 256, 256, 0, stream>>>((const float4*)src, dst, n4);
  };
  conv_w(wq, wq_b, (size_t)L_LAYERS * D_ * D_);
  conv_w(wk, wk_b, (size_t)L_LAYERS * D_ * D_);
  conv_w(wv, wv_b, (size_t)L_LAYERS * D_ * D_);
  conv_w(wo, wo_b, (size_t)L_LAYERS * D_ * D_);
  conv_w(proj, pj_b, (size_t)L_LAYERS * M_ * DH_);
  conv_w(pw1_w, p1_b, (size_t)L_LAYERS * 2048 * D_);
  conv_w(pw2_w, p2_b, (size_t)L_LAYERS * D_ * INNER_);

  for (int l = 0; l < L_LAYERS; l++) {
    const ushort* wql = wq_b + (size_t)l * D_ * D_;
    const ushort* wkl = wk_b + (size_t)l * D_ * D_;
    const ushort* wvl = wv_b + (size_t)l * D_ * D_;
    const ushort* wol = wo_b + (size_t)l * D_ * D_;
    const ushort* pjl = pj_b + (size_t)l * M_ * DH_;
    const ushort* p1l = p1_b + (size_t)l * 2048 * D_;
    const ushort* p2l = p2_b + (size_t)l * D_ * INNER_;
    const float*  dwl = dw_w + (size_t)l * INNER_ * 31;
    const float*  xin = (l == 0) ? in_x : x;   // layer-0 reads the input directly
    float* xout = (l == L_LAYERS - 1) ? (float*)d_out : x;

    ln_kernel<<<T_, 256, 0, stream>>>(xin, ln1_g + l * D_, ln1_b + l * D_, h);
    gemm_mfma<false, true><<<dim3(T_ / 128, 4), 256, 0, stream>>>(h, wql, bq + l * D_, nullptr, q, T_, D_, D_, D_, D_);
    gemm_mfma<false, true><<<dim3(T_ / 128, 4), 256, 0, stream>>>(h, wkl, bk + l * D_, nullptr, k, T_, D_, D_, D_, D_);
    gemm_mfma<false, true><<<dim3(T_ / 128, 4), 256, 0, stream>>>(h, wvl, bv + l * D_, nullptr, v, T_, D_, D_, D_, D_);
    // kp features (bf16, stride 320, zero-padded cols >= 266)
    gemm_mfma<false, true><<<dim3(ROWS_ / 128, 3), 256, 0, stream>>>(k, pjl, nullptr, nullptr, p, ROWS_, M_, DH_, PS_, PS_);
    phi_epilogue<<<ROWS_ / 4, 256, 0, stream>>>(p, k, 0);
    ctx_mfma<<<dim3(32, 5, 8), 256, 0, stream>>>(p, v, part, kpart);
    ctx_reduce<<<dim3(32, 5), 256, 0, stream>>>(part, kpart, ctxb, ksum);
    // qp features
    gemm_mfma<false, true><<<dim3(ROWS_ / 128, 3), 256, 0, stream>>>(q, pjl, nullptr, nullptr, p, ROWS_, M_, DH_, PS_, PS_);
    phi_epilogue<<<ROWS_ / 4, 256, 0, stream>>>(p, q, 1);
    attn_out_mfma<<<dim3(32, 32), 256, 0, stream>>>(p, ctxb, ksum, obuf);
    // x = x + o @ wo^T + bo
    gemm_mfma<true, false><<<dim3(T_ / 128, 4), 256, 0, stream>>>(obuf, wol, bo + l * D_, xin, x, T_, D_, D_, D_, D_);
    // FF branch
    ln_kernel<<<T_, 256, 0, stream>>>(x, ln2_g + l * D_, ln2_b + l * D_, h);
    gemm_mfma<false, true><<<dim3(T_ / 128, 16), 256, 0, stream>>>(h, p1l, pw1_b + l * 2048, nullptr, y, T_, 2048, D_, 2048, 2048);
    glu_kernel<<<T_ * INNER_ / 8 / 256, 256, 0, stream>>>(y, glu);
    dwconv_kernel<<<B_ * (N_ / TN_) * 4, 256, 0, stream>>>(glu, dwl, dw_b + l * INNER_, conv);
    gemm_mfma<true, false><<<dim3(T_ / 128, 4), 256, 0, stream>>>(conv, p2l, pw2_b + l * D_, x, xout, T_, D_, INNER_, D_, D_);
  }
}

// Round 5
// 1494.425 us; speedup vs baseline: 6.2313x; 1.3896x over previous
//
#include <hip/hip_runtime.h>

// PCmer forward: bf16-MFMA, global_load_lds staging, fused phi (GEMM+FAVOR epilogue),
// fused QKV, ksum fused into ctx, dinv fused into attn_out.
// L=6, B=4, N=2048, D=512, H=8, DH=64, ID=512, M=266, INNER=1024, K=31.

#define L_LAYERS 6
#define B_ 4
#define N_ 2048
#define D_ 512
#define H_ 8
#define DH_ 64
#define M_ 266
#define INNER_ 1024
#define T_ 8192            // B*N tokens
#define ROWS_ 65536        // B*N*H rows for phi
#define PS_ 320            // padded row stride for qp/kp (zeros in [266,320))
#define QKVS_ 1536         // qkv row stride

typedef __attribute__((ext_vector_type(8))) short short8;
typedef __attribute__((ext_vector_type(4))) float floatx4;

__device__ __forceinline__ ushort f2bf(float f) {
  union { float f; uint u; } v; v.f = f;
  uint r = v.u + 0x7fffu + ((v.u >> 16) & 1u);
  return (ushort)(r >> 16);
}
__device__ __forceinline__ float bf2f(ushort u) {
  union { uint u; float f; } v; v.u = ((uint)u) << 16;
  return v.f;
}
__device__ __forceinline__ float wave_sum(float v) {
#pragma unroll
  for (int m = 1; m < 64; m <<= 1) v += __shfl_xor(v, m);
  return v;
}
// async global->LDS, 16B per lane; dest = wave-uniform base + lane*16
__device__ __forceinline__ void async_cp16(const void* g, void* l) {
  __builtin_amdgcn_global_load_lds(
      (const __attribute__((address_space(1))) void*)g,
      (__attribute__((address_space(3))) void*)l, 16, 0, 0);
}

// ---------------- weight packing ----------------
__global__ void f2bf4_kernel(const float4* __restrict__ in, ushort* __restrict__ out, int n4) {
  int i = blockIdx.x * 256 + threadIdx.x;
  if (i < n4) {
    float4 v = in[i];
    ushort4 r;
    r.x = f2bf(v.x); r.y = f2bf(v.y); r.z = f2bf(v.z); r.w = f2bf(v.w);
    *(ushort4*)(out + (size_t)i * 4) = r;
  }
}
__global__ void pack_qkv_w(const float4* __restrict__ src, ushort* __restrict__ dst, int off) {
  int i = blockIdx.x * 256 + threadIdx.x;   // L*512*128
  if (i >= L_LAYERS * 512 * 128) return;
  int l = i >> 16;                          // / (512*128)
  int rem = i & 65535;
  int row = rem >> 7, c4 = rem & 127;
  float4 v = src[i];
  ushort4 r;
  r.x = f2bf(v.x); r.y = f2bf(v.y); r.z = f2bf(v.z); r.w = f2bf(v.w);
  *(ushort4*)(dst + ((size_t)l * QKVS_ + off + row) * 512 + c4 * 4) = r;
}
__global__ void pack_qkv_b(const float* __restrict__ bq, const float* __restrict__ bk,
                           const float* __restrict__ bv, float* __restrict__ dst) {
  int i = blockIdx.x * 256 + threadIdx.x;   // L*1536
  if (i >= L_LAYERS * QKVS_) return;
  int l = i / QKVS_, c = i % QKVS_;
  dst[i] = c < 512 ? bq[l * 512 + c] : (c < 1024 ? bk[l * 512 + c - 512] : bv[l * 512 + c - 1024]);
}
__global__ void pad_proj(const float* __restrict__ proj, ushort* __restrict__ dst) {
  int i = blockIdx.x * 256 + threadIdx.x;   // L*320*64
  if (i >= L_LAYERS * 320 * 64) return;
  int l = i / (320 * 64), rem = i % (320 * 64), m = rem >> 6, kk = rem & 63;
  dst[i] = (m < M_) ? f2bf(proj[((size_t)l * M_ + m) * 64 + kk]) : (ushort)0;
}

// ---------------- layernorm (block per token, D=512), bf16 out ----------------
__global__ __launch_bounds__(256) void ln_kernel(const float* __restrict__ x,
                                                 const float* __restrict__ g,
                                                 const float* __restrict__ b,
                                                 ushort* __restrict__ out) {
  const int t = blockIdx.x;
  const int tid = threadIdx.x;
  const float* row = x + (size_t)t * D_;
  float v0 = row[tid], v1 = row[tid + 256];
  float s1 = v0 + v1;
  float s2 = v0 * v0 + v1 * v1;
  s1 = wave_sum(s1);
  s2 = wave_sum(s2);
  __shared__ float sh1[4], sh2[4];
  int w = tid >> 6;
  if ((tid & 63) == 0) { sh1[w] = s1; sh2[w] = s2; }
  __syncthreads();
  s1 = sh1[0] + sh1[1] + sh1[2] + sh1[3];
  s2 = sh2[0] + sh2[1] + sh2[2] + sh2[3];
  float mu = s1 * (1.f / D_);
  float var = s2 * (1.f / D_) - mu * mu;
  float rs = rsqrtf(var + 1e-5f);
  out[(size_t)t * D_ + tid]       = f2bf((v0 - mu) * rs * g[tid] + b[tid]);
  out[(size_t)t * D_ + tid + 256] = f2bf((v1 - mu) * rs * g[tid + 256] + b[tid + 256]);
}

// ---------------- bf16 MFMA GEMM (global_load_lds staging, XOR-swizzled LDS) -----------------
// C[t][n] = sum_k A[t][k]*W[n][k] + bias[n] (+res). 128x128 tile, BK=32, 4 waves.
// Requires: grid covers T/128 x Nn/128 exactly; K % 32 == 0; A row stride = K.
template <bool HAS_RES, bool OUT_BF16>
__global__ __launch_bounds__(256) void gemm_mfma(const ushort* __restrict__ A,
                                                 const ushort* __restrict__ W,
                                                 const float* __restrict__ bias,
                                                 const float* __restrict__ res,
                                                 void* __restrict__ Cout,
                                                 int K, int ldc) {
  __shared__ ushort As[128 * 32];   // row-major stride 32 ushorts, chunk-swizzled
  __shared__ ushort Bs[128 * 32];
  const int tid = threadIdx.x;
  const int w = tid >> 6, lane = tid & 63;
  const int row0 = blockIdx.x * 128, col0 = blockIdx.y * 128;
  // staging: lane -> row rl=lane>>2 within 16-row group, logical chunk (lane&3)^((lane>>3)&3)
  const int rl = lane >> 2;
  const int lc = ((lane & 3) ^ ((lane >> 3) & 3)) * 8;   // logical ushort offset
  const ushort* gA0 = A + (size_t)(row0 + w * 32 + rl) * K + lc;
  const ushort* gA1 = gA0 + (size_t)16 * K;
  const ushort* gB0 = W + (size_t)(col0 + w * 32 + rl) * K + lc;
  const ushort* gB1 = gB0 + (size_t)16 * K;
  ushort* lA = As + w * 1024;   // wave's 32 rows
  ushort* lB = Bs + w * 1024;
  const int m16 = lane & 15, quad = lane >> 4;
  const int awr = (w >> 1) * 64, bwc = (w & 1) * 64;
  floatx4 acc[4][4] = {};
  for (int k0 = 0; k0 < K; k0 += 32) {
    __syncthreads();
    async_cp16(gA0 + k0, lA);
    async_cp16(gA1 + k0, lA + 512);
    async_cp16(gB0 + k0, lB);
    async_cp16(gB1 + k0, lB + 512);
    __syncthreads();
    short8 af[4], bfr[4];
#pragma unroll
    for (int i = 0; i < 4; i++) {
      int r = awr + i * 16 + m16;
      af[i] = *(const short8*)&As[r * 32 + (quad ^ ((r >> 1) & 3)) * 8];
    }
#pragma unroll
    for (int j = 0; j < 4; j++) {
      int r = bwc + j * 16 + m16;
      bfr[j] = *(const short8*)&Bs[r * 32 + (quad ^ ((r >> 1) & 3)) * 8];
    }
#pragma unroll
    for (int i = 0; i < 4; i++)
#pragma unroll
      for (int j = 0; j < 4; j++)
        acc[i][j] = __builtin_amdgcn_mfma_f32_16x16x32_bf16(af[i], bfr[j], acc[i][j], 0, 0, 0);
  }
#pragma unroll
  for (int i = 0; i < 4; i++) {
    const int r0 = row0 + awr + i * 16 + quad * 4;
#pragma unroll
    for (int j = 0; j < 4; j++) {
      const int c = col0 + bwc + j * 16 + m16;
      const float bv = bias[c];
#pragma unroll
      for (int r = 0; r < 4; r++) {
        float vv = acc[i][j][r] + bv;
        if (HAS_RES) vv += res[(size_t)(r0 + r) * ldc + c];
        if (OUT_BF16) ((ushort*)Cout)[(size_t)(r0 + r) * ldc + c] = f2bf(vv);
        else          ((float*)Cout)[(size_t)(r0 + r) * ldc + c] = vv;
      }
    }
  }
}

// ---------------- fused phi: GEMM(64 rows x 320 cols, K=64) + FAVOR epilogue ----------------
// data = qkv + col-offset (q:0, k:512); phi rows trow=(b*N+n)*H+h -> qkv row trow>>3, col (trow&7)*64.
// projp: [320][64] bf16 (rows >=266 zero). out: [ROWS_][PS_] bf16 final phi features.
__global__ __launch_bounds__(256) void phi_fused(const ushort* __restrict__ data,
                                                 const ushort* __restrict__ projp,
                                                 ushort* __restrict__ out,
                                                 int is_query) {
  __shared__ ushort Bs[320 * 64];   // 40 KB, row-major stride 64, 8-chunk swizzle
  __shared__ ushort As[64 * 64];    // 8 KB
  __shared__ float diag_sh[64];
  const int t0 = blockIdx.x * 64;
  const int tid = threadIdx.x;
  const int w = tid >> 6, lane = tid & 63;
  const int rl8 = lane >> 3;                        // row within 8-row group
  const int lc8 = ((lane & 7) ^ (rl8 & 7)) * 8;     // logical ushort offset
  // stage B: wave w rows [w*80, w*80+80)
#pragma unroll
  for (int j = 0; j < 10; j++) {
    const int rb = w * 80 + j * 8;
    async_cp16(projp + (size_t)(rb + rl8) * 64 + lc8, Bs + rb * 64);
  }
  // stage A: wave w rows t0 + w*16 + [0,16)
#pragma unroll
  for (int j = 0; j < 2; j++) {
    const int rb = w * 16 + j * 8;
    const int trow = t0 + rb + rl8;
    async_cp16(data + (size_t)(trow >> 3) * QKVS_ + (trow & 7) * 64 + lc8, As + rb * 64);
  }
  __syncthreads();
  // diag: 4 lanes per row (wave w owns rows w*16..w*16+16)
  {
    const int r = w * 16 + (lane >> 2);
    const int c0 = 2 * (lane & 3);
    float s = 0.f;
#pragma unroll
    for (int cc = 0; cc < 2; cc++) {
      short8 vv = *(const short8*)&As[r * 64 + ((c0 + cc) ^ (r & 7)) * 8];
      const ushort* u = (const ushort*)&vv;
#pragma unroll
      for (int j = 0; j < 8; j++) { float f = bf2f(u[j]); s += f * f; }
    }
    s += __shfl_xor(s, 1);
    s += __shfl_xor(s, 2);
    if ((lane & 3) == 0) diag_sh[r] = 0.0625f * s;   // 0.5*dn^2
  }
  __syncthreads();
  const int l16 = lane & 15, quad = lane >> 4;
  floatx4 acc[20];
#pragma unroll
  for (int cf = 0; cf < 20; cf++) acc[cf] = (floatx4){0.f, 0.f, 0.f, 0.f};
  const int ar = w * 16 + l16;
#pragma unroll
  for (int s = 0; s < 2; s++) {
    short8 af = *(const short8*)&As[ar * 64 + ((s * 4 + quad) ^ (ar & 7)) * 8];
#pragma unroll
    for (int cf = 0; cf < 20; cf++) {
      const int br = cf * 16 + l16;
      short8 bf = *(const short8*)&Bs[br * 64 + ((s * 4 + quad) ^ (br & 7)) * 8];
      acc[cf] = __builtin_amdgcn_mfma_f32_16x16x32_bf16(af, bf, acc[cf], 0, 0, 0);
    }
  }
  const float dn = 0.35355339059327373f;      // 64^-0.25
  const float ratio = 0.06131393394849658f;   // 266^-0.5
  float dg[4];
#pragma unroll
  for (int r = 0; r < 4; r++) dg[r] = diag_sh[w * 16 + quad * 4 + r];
#pragma unroll
  for (int r = 0; r < 4; r++) {
    const int trow = t0 + w * 16 + quad * 4 + r;
    ushort* orow = out + (size_t)trow * PS_;
    if (is_query) {
      float mx = -1e30f;
#pragma unroll
      for (int cf = 0; cf < 20; cf++) {
        const int col = cf * 16 + l16;
        if (col < M_) mx = fmaxf(mx, dn * acc[cf][r]);
      }
      mx = fmaxf(mx, __shfl_xor(mx, 1));
      mx = fmaxf(mx, __shfl_xor(mx, 2));
      mx = fmaxf(mx, __shfl_xor(mx, 4));
      mx = fmaxf(mx, __shfl_xor(mx, 8));
#pragma unroll
      for (int cf = 0; cf < 20; cf++) {
        const int col = cf * 16 + l16;
        float val = (col < M_) ? ratio * (expf(dn * acc[cf][r] - dg[r] - mx) + 1e-4f) : 0.f;
        orow[col] = f2bf(val);
      }
    } else {
#pragma unroll
      for (int cf = 0; cf < 20; cf++) {
        const int col = cf * 16 + l16;
        float val = (col < M_) ? ratio * expf(dn * acc[cf][r] - dg[r] + 1e-4f) : 0.f;
        orow[col] = f2bf(val);
      }
    }
  }
}

// ---------------- ctx partials + ksum partials: MFMA over n-chunk of 256 ----------------
// grid (bh=32, mt=5, ns=8). part[bh][ns][mt][64m][64e] fp32; kpart[bh][ns][mt][64m].
__global__ __launch_bounds__(256) void ctx_mfma(const ushort* __restrict__ kp,
                                                const ushort* __restrict__ qkv,
                                                float* __restrict__ part,
                                                float* __restrict__ kpart) {
  __shared__ ushort kps[64][40];   // [m][n-chunk32], XOR-group swizzled
  __shared__ ushort vsT[64][40];   // [e][n-chunk32], XOR-group swizzled
  __shared__ float kshare[4][64];
  const int bh = blockIdx.x, mt = blockIdx.y, ns = blockIdx.z;
  const int b = bh >> 3, h = bh & 7;
  const int m0 = mt * 64;
  const int tid = threadIdx.x;
  const int w = tid >> 6, lane = tid & 63, l16 = lane & 15, quad = lane >> 4;
  const int nn = tid >> 3;       // 0..31
  const int a8 = tid & 7;        // row octet
  const int gn = nn >> 3, jn = nn & 7;
  const int pc = ((gn ^ (a8 & 3)) << 3) | jn;
  const int km = tid & 63, kg = tid >> 6;  // ksum mapping
  floatx4 acc[4] = {};
  float ksp = 0.f;
  for (int nstep = 0; nstep < 8; nstep++) {
    const int n0 = ns * 256 + nstep * 32;
    const size_t trow = (size_t)((b * N_ + n0 + nn) * H_ + h);
    uint4 kv = *(const uint4*)(kp + trow * PS_ + m0 + a8 * 8);
    uint4 vv = *(const uint4*)(qkv + ((size_t)(b * N_ + n0 + nn)) * QKVS_ + 1024 + h * 64 + a8 * 8);
    __syncthreads();
    const ushort* ke = (const ushort*)&kv;
    const ushort* ve = (const ushort*)&vv;
#pragma unroll
    for (int j = 0; j < 8; j++) kps[a8 * 8 + j][pc] = ke[j];
#pragma unroll
    for (int j = 0; j < 8; j++) vsT[a8 * 8 + j][pc] = ve[j];
    __syncthreads();
    const int am = w * 16 + l16;
    const int apg = quad ^ ((am >> 3) & 3);
    short8 af = *(const short8*)&kps[am][apg * 8];
#pragma unroll
    for (int et = 0; et < 4; et++) {
      const int be = et * 16 + l16;
      const int bpg = quad ^ ((be >> 3) & 3);
      short8 bf = *(const short8*)&vsT[be][bpg * 8];
      acc[et] = __builtin_amdgcn_mfma_f32_16x16x32_bf16(af, bf, acc[et], 0, 0, 0);
    }
    {
      short8 kr = *(const short8*)&kps[km][kg * 8];
      const ushort* ku = (const ushort*)&kr;
#pragma unroll
      for (int j = 0; j < 8; j++) ksp += bf2f(ku[j]);
    }
  }
  float* pb = part + ((size_t)(bh * 8 + ns) * 5 + mt) * 4096;
#pragma unroll
  for (int et = 0; et < 4; et++)
#pragma unroll
    for (int r = 0; r < 4; r++)
      pb[(w * 16 + quad * 4 + r) * 64 + et * 16 + l16] = acc[et][r];
  kshare[kg][km] = ksp;
  __syncthreads();
  if (tid < 64)
    kpart[((size_t)(bh * 8 + ns) * 5 + mt) * 64 + tid] =
        kshare[0][tid] + kshare[1][tid] + kshare[2][tid] + kshare[3][tid];
}

// ---------------- reduce partials -> ctxb bf16 [bh][288][64] + ksum[bh][PS_] ----------------
__global__ __launch_bounds__(256) void ctx_reduce(const float* __restrict__ part,
                                                  const float* __restrict__ kpart,
                                                  ushort* __restrict__ ctxb,
                                                  float* __restrict__ ksum) {
  const int bh = blockIdx.x, mt = blockIdx.y;
  const int tid = threadIdx.x;
  for (int idx = tid; idx < 4096; idx += 256) {
    float s = 0.f;
#pragma unroll
    for (int ns = 0; ns < 8; ns++)
      s += part[((size_t)(bh * 8 + ns) * 5 + mt) * 4096 + idx];
    int m = mt * 64 + (idx >> 6);
    if (m < 288) ctxb[((size_t)bh * 288 + m) * 64 + (idx & 63)] = f2bf(s);
  }
  if (tid < 64) {
    float s = 0.f;
#pragma unroll
    for (int ns = 0; ns < 8; ns++)
      s += kpart[((size_t)(bh * 8 + ns) * 5 + mt) * 64 + tid];
    ksum[(size_t)bh * PS_ + mt * 64 + tid] = s;
  }
}

// ---------------- attention out (dinv fused): o = dinv * (qp @ ctxb) ----------------
__global__ __launch_bounds__(256) void attn_out_mfma(const ushort* __restrict__ qp,
                                                     const ushort* __restrict__ ctxb,
                                                     const float* __restrict__ ksum,
                                                     ushort* __restrict__ o) {
  __shared__ ushort qs[64][40];
  __shared__ ushort cs[64][40];
  __shared__ float ks_sh[PS_];
  __shared__ float dsh[64];
  const int bh = blockIdx.x, b = bh >> 3, h = bh & 7;
  const int n0 = blockIdx.y * 64;
  const int tid = threadIdx.x;
  const int w = tid >> 6, lane = tid & 63, l16 = lane & 15, quad = lane >> 4;
  const int qn = tid >> 2, qms = (tid & 3) * 8;
  const int cm = tid >> 3, ca8 = tid & 7;
  const int gm = cm >> 3, jm = cm & 7;
  const int pcc = ((gm ^ (ca8 & 3)) << 3) | jm;
  for (int i = tid; i < PS_; i += 256) ks_sh[i] = ksum[(size_t)bh * PS_ + i];
  floatx4 acc[4] = {};
  float dacc = 0.f;
  for (int m0 = 0; m0 < 288; m0 += 32) {
    uint4 qv = *(const uint4*)(qp + ((size_t)((b * N_ + n0 + qn) * H_ + h)) * PS_ + m0 + qms);
    uint4 cv = *(const uint4*)(ctxb + ((size_t)bh * 288 + m0 + cm) * 64 + ca8 * 8);
    __syncthreads();
    *(uint4*)&qs[qn][qms] = qv;
    const ushort* ce = (const ushort*)&cv;
#pragma unroll
    for (int j = 0; j < 8; j++) cs[ca8 * 8 + j][pcc] = ce[j];
    const ushort* qe = (const ushort*)&qv;
#pragma unroll
    for (int j = 0; j < 8; j++) dacc += bf2f(qe[j]) * ks_sh[m0 + qms + j];
    __syncthreads();
    short8 af = *(const short8*)&qs[w * 16 + l16][quad * 8];
#pragma unroll
    for (int et = 0; et < 4; et++) {
      const int be = et * 16 + l16;
      const int bpg = quad ^ ((be >> 3) & 3);
      short8 bf = *(const short8*)&cs[be][bpg * 8];
      acc[et] = __builtin_amdgcn_mfma_f32_16x16x32_bf16(af, bf, acc[et], 0, 0, 0);
    }
  }
  dacc += __shfl_xor(dacc, 1);
  dacc += __shfl_xor(dacc, 2);
  if ((tid & 3) == 0) dsh[qn] = 1.f / (dacc + 1e-8f);
  __syncthreads();
#pragma unroll
  for (int r = 0; r < 4; r++) {
    const int nl = w * 16 + quad * 4 + r;
    const int n = n0 + nl;
    const float di = dsh[nl];
#pragma unroll
    for (int et = 0; et < 4; et++)
      o[((size_t)(b * N_ + n)) * 512 + h * 64 + et * 16 + l16] = f2bf(acc[et][r] * di);
  }
}

// ---------------- GLU bf16 ----------------
__global__ void glu_kernel(const ushort* __restrict__ y, ushort* __restrict__ out) {
  int i = blockIdx.x * 256 + threadIdx.x;  // over T*1024/8
  int t = i >> 7, c8 = (i & 127) * 8;
  uint4 av = *(const uint4*)(y + (size_t)t * 2048 + c8);
  uint4 gv = *(const uint4*)(y + (size_t)t * 2048 + 1024 + c8);
  const ushort* ae = (const ushort*)&av;
  const ushort* ge = (const ushort*)&gv;
  ushort r[8];
#pragma unroll
  for (int j = 0; j < 8; j++) {
    float fa = bf2f(ae[j]), fg = bf2f(ge[j]);
    r[j] = f2bf(fa / (1.f + expf(-fg)));
  }
  *(uint4*)(out + (size_t)i * 8) = *(uint4*)r;
}

// ---------------- depthwise conv K=31, pad 15, + bias + silu; bf16 in/out ----------------
#define TN_ 16
__global__ __launch_bounds__(256) void dwconv_kernel(const ushort* __restrict__ x,
                                                     const float* __restrict__ w,
                                                     const float* __restrict__ bias,
                                                     ushort* __restrict__ out) {
  const int bid = blockIdx.x;
  const int cb = bid & 3;
  const int nb = (bid >> 2) & 127;
  const int b  = bid >> 9;
  const int c = cb * 256 + threadIdx.x;
  const int n0 = nb * TN_;
  float win[TN_ + 30];
#pragma unroll
  for (int i = 0; i < TN_ + 30; i++) {
    int nn = n0 + i - 15;
    win[i] = (nn >= 0 && nn < N_) ? bf2f(x[(size_t)(b * N_ + nn) * INNER_ + c]) : 0.f;
  }
  float wc[31];
#pragma unroll
  for (int kk = 0; kk < 31; kk++) wc[kk] = w[c * 31 + kk];
  const float bsv = bias[c];
#pragma unroll
  for (int j = 0; j < TN_; j++) {
    float acc = bsv;
#pragma unroll
    for (int kk = 0; kk < 31; kk++) acc += win[j + kk] * wc[kk];
    acc = acc / (1.f + expf(-acc));
    out[(size_t)(b * N_ + n0 + j) * INNER_ + c] = f2bf(acc);
  }
}

// ---------------- host ----------------
extern "C" void kernel_launch(void* const* d_in, const int* in_sizes, int n_in,
                              void* d_out, int out_size, void* d_ws, size_t ws_size,
                              hipStream_t stream) {
  const float* in_x  = (const float*)d_in[0];
  const float* ln1_g = (const float*)d_in[1];
  const float* ln1_b = (const float*)d_in[2];
  const float* wq    = (const float*)d_in[3];
  const float* bq    = (const float*)d_in[4];
  const float* wk    = (const float*)d_in[5];
  const float* bk    = (const float*)d_in[6];
  const float* wv    = (const float*)d_in[7];
  const float* bv    = (const float*)d_in[8];
  const float* wo    = (const float*)d_in[9];
  const float* bo    = (const float*)d_in[10];
  const float* proj  = (const float*)d_in[11];
  const float* ln2_g = (const float*)d_in[12];
  const float* ln2_b = (const float*)d_in[13];
  const float* pw1_w = (const float*)d_in[14];
  const float* pw1_b = (const float*)d_in[15];
  const float* dw_w  = (const float*)d_in[16];
  const float* dw_b  = (const float*)d_in[17];
  const float* pw2_w = (const float*)d_in[18];
  const float* pw2_b = (const float*)d_in[19];

  char* cur = (char*)d_ws;
  auto alloc = [&](size_t bytes) { char* p = cur; cur += (bytes + 255) & ~(size_t)255; return p; };
  float*  x    = (float*)alloc((size_t)T_ * D_ * 4);
  ushort* p    = (ushort*)alloc((size_t)ROWS_ * PS_ * 2);      // qp/kp; glu+conv alias
  float*  part = (float*)alloc((size_t)32 * 8 * 5 * 4096 * 4); // ctx partials
  float*  kpart= (float*)alloc((size_t)32 * 8 * 5 * 64 * 4);   // ksum partials
  ushort* ctxb = (ushort*)alloc((size_t)32 * 288 * 64 * 2);
  float*  ksum = (float*)alloc((size_t)32 * PS_ * 4);
  ushort* y    = (ushort*)alloc((size_t)T_ * 2048 * 2);
  ushort* h    = (ushort*)alloc((size_t)T_ * D_ * 2);
  ushort* qkv  = (ushort*)alloc((size_t)T_ * QKVS_ * 2);
  ushort* obuf = (ushort*)alloc((size_t)T_ * D_ * 2);
  ushort* wqkv_b = (ushort*)alloc((size_t)L_LAYERS * QKVS_ * 512 * 2);
  float*  bqkv   = (float*)alloc((size_t)L_LAYERS * QKVS_ * 4);
  ushort* wo_b = (ushort*)alloc((size_t)L_LAYERS * D_ * D_ * 2);
  ushort* pjp  = (ushort*)alloc((size_t)L_LAYERS * 320 * 64 * 2);
  ushort* p1_b = (ushort*)alloc((size_t)L_LAYERS * 2048 * D_ * 2);
  ushort* p2_b = (ushort*)alloc((size_t)L_LAYERS * D_ * INNER_ * 2);
  ushort* glu  = p;
  ushort* conv = p + (size_t)T_ * INNER_;

  // weight packing (same work every call; graph-capture safe)
  pack_qkv_w<<<(L_LAYERS * 512 * 128 + 255) / 256, 256, 0, stream>>>((const float4*)wq, wqkv_b, 0);
  pack_qkv_w<<<(L_LAYERS * 512 * 128 + 255) / 256, 256, 0, stream>>>((const float4*)wk, wqkv_b, 512);
  pack_qkv_w<<<(L_LAYERS * 512 * 128 + 255) / 256, 256, 0, stream>>>((const float4*)wv, wqkv_b, 1024);
  pack_qkv_b<<<(L_LAYERS * QKVS_ + 255) / 256, 256, 0, stream>>>(bq, bk, bv, bqkv);
  pad_proj<<<(L_LAYERS * 320 * 64 + 255) / 256, 256, 0, stream>>>(proj, pjp);
  auto conv_w = [&](const float* src, ushort* dst, size_t n) {
    int n4 = (int)(n / 4);
    f2bf4_kernel<<<(n4 + 255) / 256, 256, 0, stream>>>((const float4*)src, dst, n4);
  };
  conv_w(wo, wo_b, (size_t)L_LAYERS * D_ * D_);
  conv_w(pw1_w, p1_b, (size_t)L_LAYERS * 2048 * D_);
  conv_w(pw2_w, p2_b, (size_t)L_LAYERS * D_ * INNER_);

  for (int l = 0; l < L_LAYERS; l++) {
    const ushort* wqkvl = wqkv_b + (size_t)l * QKVS_ * 512;
    const ushort* wol = wo_b + (size_t)l * D_ * D_;
    const ushort* pjl = pjp + (size_t)l * 320 * 64;
    const ushort* p1l = p1_b + (size_t)l * 2048 * D_;
    const ushort* p2l = p2_b + (size_t)l * D_ * INNER_;
    const float*  dwl = dw_w + (size_t)l * INNER_ * 31;
    const float*  xin = (l == 0) ? in_x : x;
    float* xout = (l == L_LAYERS - 1) ? (float*)d_out : x;

    ln_kernel<<<T_, 256, 0, stream>>>(xin, ln1_g + l * D_, ln1_b + l * D_, h);
    // qkv = h @ Wqkv^T + b  (one GEMM, N=1536)
    gemm_mfma<false, true><<<dim3(T_ / 128, QKVS_ / 128), 256, 0, stream>>>(
        h, wqkvl, bqkv + (size_t)l * QKVS_, nullptr, qkv, D_, QKVS_);
    // kp features
    phi_fused<<<ROWS_ / 64, 256, 0, stream>>>(qkv + 512, pjl, p, 0);
    ctx_mfma<<<dim3(32, 5, 8), 256, 0, stream>>>(p, qkv, part, kpart);
    ctx_reduce<<<dim3(32, 5), 256, 0, stream>>>(part, kpart, ctxb, ksum);
    // qp features
    phi_fused<<<ROWS_ / 64, 256, 0, stream>>>(qkv, pjl, p, 1);
    attn_out_mfma<<<dim3(32, 32), 256, 0, stream>>>(p, ctxb, ksum, obuf);
    // x = x + o @ wo^T + bo
    gemm_mfma<true, false><<<dim3(T_ / 128, 4), 256, 0, stream>>>(
        obuf, wol, bo + l * D_, xin, x, D_, D_);
    // FF branch
    ln_kernel<<<T_, 256, 0, stream>>>(x, ln2_g + l * D_, ln2_b + l * D_, h);
    gemm_mfma<false, true><<<dim3(T_ / 128, 16), 256, 0, stream>>>(
        h, p1l, pw1_b + (size_t)l * 2048, nullptr, y, D_, 2048);
    glu_kernel<<<T_ * INNER_ / 8 / 256, 256, 0, stream>>>(y, glu);
    dwconv_kernel<<<B_ * (N_ / TN_) * 4, 256, 0, stream>>>(glu, dwl, dw_b + l * INNER_, conv);
    gemm_mfma<true, false><<<dim3(T_ / 128, 4), 256, 0, stream>>>(
        conv, p2l, pw2_b + l * D_, x, xout, INNER_, D_);
  }
}

// Round 6
// 1415.146 us; speedup vs baseline: 6.5804x; 1.0560x over previous
//
#include <hip/hip_runtime.h>

// PCmer forward: bf16-MFMA, global_load_lds staging, fused phi_k, fused phi_q+dinv+attn_out,
// GLU fused into pw1 (interleaved weights), fused QKV, ksum fused into ctx.
// L=6, B=4, N=2048, D=512, H=8, DH=64, ID=512, M=266, INNER=1024, K=31.

#define L_LAYERS 6
#define B_ 4
#define N_ 2048
#define D_ 512
#define H_ 8
#define DH_ 64
#define M_ 266
#define INNER_ 1024
#define T_ 8192            // B*N tokens
#define ROWS_ 65536        // B*N*H rows for phi
#define PS_ 320            // padded row stride for kp (zeros in [266,320))
#define QKVS_ 1536         // qkv row stride
#define NS_ 4              // ctx n-splits

typedef __attribute__((ext_vector_type(8))) short short8;
typedef __attribute__((ext_vector_type(4))) float floatx4;

__device__ __forceinline__ ushort f2bf(float f) {
  union { float f; uint u; } v; v.f = f;
  uint r = v.u + 0x7fffu + ((v.u >> 16) & 1u);
  return (ushort)(r >> 16);
}
__device__ __forceinline__ float bf2f(ushort u) {
  union { uint u; float f; } v; v.u = ((uint)u) << 16;
  return v.f;
}
__device__ __forceinline__ float wave_sum(float v) {
#pragma unroll
  for (int m = 1; m < 64; m <<= 1) v += __shfl_xor(v, m);
  return v;
}
// async global->LDS, 16B per lane; dest = wave-uniform base + lane*16 (src per-lane)
__device__ __forceinline__ void async_cp16(const void* g, void* l) {
  __builtin_amdgcn_global_load_lds(
      (const __attribute__((address_space(1))) void*)g,
      (__attribute__((address_space(3))) void*)l, 16, 0, 0);
}

// ---------------- weight packing ----------------
__global__ void f2bf4_kernel(const float4* __restrict__ in, ushort* __restrict__ out, int n4) {
  int i = blockIdx.x * 256 + threadIdx.x;
  if (i < n4) {
    float4 v = in[i];
    ushort4 r;
    r.x = f2bf(v.x); r.y = f2bf(v.y); r.z = f2bf(v.z); r.w = f2bf(v.w);
    *(ushort4*)(out + (size_t)i * 4) = r;
  }
}
__global__ void pack_qkv_w(const float4* __restrict__ src, ushort* __restrict__ dst, int off) {
  int i = blockIdx.x * 256 + threadIdx.x;   // L*512*128
  if (i >= L_LAYERS * 512 * 128) return;
  int l = i >> 16;
  int rem = i & 65535;
  int row = rem >> 7, c4 = rem & 127;
  float4 v = src[i];
  ushort4 r;
  r.x = f2bf(v.x); r.y = f2bf(v.y); r.z = f2bf(v.z); r.w = f2bf(v.w);
  *(ushort4*)(dst + ((size_t)l * QKVS_ + off + row) * 512 + c4 * 4) = r;
}
__global__ void pack_qkv_b(const float* __restrict__ bq, const float* __restrict__ bk,
                           const float* __restrict__ bv, float* __restrict__ dst) {
  int i = blockIdx.x * 256 + threadIdx.x;   // L*1536
  if (i >= L_LAYERS * QKVS_) return;
  int l = i / QKVS_, c = i % QKVS_;
  dst[i] = c < 512 ? bq[l * 512 + c] : (c < 1024 ? bk[l * 512 + c - 512] : bv[l * 512 + c - 1024]);
}
__global__ void pad_proj(const float* __restrict__ proj, ushort* __restrict__ dst) {
  int i = blockIdx.x * 256 + threadIdx.x;   // L*320*64
  if (i >= L_LAYERS * 320 * 64) return;
  int l = i / (320 * 64), rem = i % (320 * 64), m = rem >> 6, kk = rem & 63;
  dst[i] = (m < M_) ? f2bf(proj[((size_t)l * M_ + m) * 64 + kk]) : (ushort)0;
}
// pw1 interleave: out col c' = 32b+16s+j16 -> src row s*1024 + 16b + j16 (a/g pairs share a tile)
__global__ void pack_pw1_w(const float4* __restrict__ src, ushort* __restrict__ dst) {
  int i = blockIdx.x * 256 + threadIdx.x;   // L*2048*128
  if (i >= L_LAYERS * 2048 * 128) return;
  int l = i >> 18;
  int rem = i & 262143;
  int cp = rem >> 7, c4 = rem & 127;
  int s = (cp >> 4) & 1;
  int srow = ((cp >> 5) << 4) + (cp & 15) + s * 1024;
  float4 v = src[((size_t)l * 2048 + srow) * 128 + c4];
  ushort4 r;
  r.x = f2bf(v.x); r.y = f2bf(v.y); r.z = f2bf(v.z); r.w = f2bf(v.w);
  *(ushort4*)(dst + ((size_t)l * 2048 + cp) * 512 + c4 * 4) = r;
}
__global__ void pack_pw1_b(const float* __restrict__ src, float* __restrict__ dst) {
  int i = blockIdx.x * 256 + threadIdx.x;   // L*2048
  if (i >= L_LAYERS * 2048) return;
  int l = i >> 11, cp = i & 2047;
  int s = (cp >> 4) & 1;
  int srow = ((cp >> 5) << 4) + (cp & 15) + s * 1024;
  dst[i] = src[l * 2048 + srow];
}

// ---------------- layernorm (block per token, D=512), bf16 out ----------------
__global__ __launch_bounds__(256) void ln_kernel(const float* __restrict__ x,
                                                 const float* __restrict__ g,
                                                 const float* __restrict__ b,
                                                 ushort* __restrict__ out) {
  const int t = blockIdx.x;
  const int tid = threadIdx.x;
  const float* row = x + (size_t)t * D_;
  float v0 = row[tid], v1 = row[tid + 256];
  float s1 = v0 + v1;
  float s2 = v0 * v0 + v1 * v1;
  s1 = wave_sum(s1);
  s2 = wave_sum(s2);
  __shared__ float sh1[4], sh2[4];
  int w = tid >> 6;
  if ((tid & 63) == 0) { sh1[w] = s1; sh2[w] = s2; }
  __syncthreads();
  s1 = sh1[0] + sh1[1] + sh1[2] + sh1[3];
  s2 = sh2[0] + sh2[1] + sh2[2] + sh2[3];
  float mu = s1 * (1.f / D_);
  float var = s2 * (1.f / D_) - mu * mu;
  float rs = rsqrtf(var + 1e-5f);
  out[(size_t)t * D_ + tid]       = f2bf((v0 - mu) * rs * g[tid] + b[tid]);
  out[(size_t)t * D_ + tid + 256] = f2bf((v1 - mu) * rs * g[tid + 256] + b[tid + 256]);
}

// ---------------- bf16 MFMA GEMM (global_load_lds staging, XOR-swizzled LDS) -----------------
// ACT 0: C = A@W^T + bias (+res), out fp32/bf16, ldc = N. ACT 1: GLU epilogue on interleaved
// columns: z = (a+ba)*sigmoid(g+bg), out bf16 at ldc=1024.
template <bool HAS_RES, bool OUT_BF16, int ACT>
__global__ __launch_bounds__(256) void gemm_mfma(const ushort* __restrict__ A,
                                                 const ushort* __restrict__ W,
                                                 const float* __restrict__ bias,
                                                 const float* __restrict__ res,
                                                 void* __restrict__ Cout,
                                                 int K, int ldc) {
  __shared__ ushort As[128 * 32];
  __shared__ ushort Bs[128 * 32];
  const int tid = threadIdx.x;
  const int w = tid >> 6, lane = tid & 63;
  const int row0 = blockIdx.x * 128, col0 = blockIdx.y * 128;
  const int rl = lane >> 2;
  const int lc = ((lane & 3) ^ ((lane >> 3) & 3)) * 8;
  const ushort* gA0 = A + (size_t)(row0 + w * 32 + rl) * K + lc;
  const ushort* gA1 = gA0 + (size_t)16 * K;
  const ushort* gB0 = W + (size_t)(col0 + w * 32 + rl) * K + lc;
  const ushort* gB1 = gB0 + (size_t)16 * K;
  ushort* lA = As + w * 1024;
  ushort* lB = Bs + w * 1024;
  const int m16 = lane & 15, quad = lane >> 4;
  const int awr = (w >> 1) * 64, bwc = (w & 1) * 64;
  floatx4 acc[4][4] = {};
  for (int k0 = 0; k0 < K; k0 += 32) {
    __syncthreads();
    async_cp16(gA0 + k0, lA);
    async_cp16(gA1 + k0, lA + 512);
    async_cp16(gB0 + k0, lB);
    async_cp16(gB1 + k0, lB + 512);
    __syncthreads();
    short8 af[4], bfr[4];
#pragma unroll
    for (int i = 0; i < 4; i++) {
      int r = awr + i * 16 + m16;
      af[i] = *(const short8*)&As[r * 32 + (quad ^ ((r >> 1) & 3)) * 8];
    }
#pragma unroll
    for (int j = 0; j < 4; j++) {
      int r = bwc + j * 16 + m16;
      bfr[j] = *(const short8*)&Bs[r * 32 + (quad ^ ((r >> 1) & 3)) * 8];
    }
#pragma unroll
    for (int i = 0; i < 4; i++)
#pragma unroll
      for (int j = 0; j < 4; j++)
        acc[i][j] = __builtin_amdgcn_mfma_f32_16x16x32_bf16(af[i], bfr[j], acc[i][j], 0, 0, 0);
  }
  if (ACT == 0) {
#pragma unroll
    for (int i = 0; i < 4; i++) {
      const int r0 = row0 + awr + i * 16 + quad * 4;
#pragma unroll
      for (int j = 0; j < 4; j++) {
        const int c = col0 + bwc + j * 16 + m16;
        const float bv = bias[c];
#pragma unroll
        for (int r = 0; r < 4; r++) {
          float vv = acc[i][j][r] + bv;
          if (HAS_RES) vv += res[(size_t)(r0 + r) * ldc + c];
          if (OUT_BF16) ((ushort*)Cout)[(size_t)(r0 + r) * ldc + c] = f2bf(vv);
          else          ((float*)Cout)[(size_t)(r0 + r) * ldc + c] = vv;
        }
      }
    }
  } else {
    // GLU: j even = a-block, j odd = g-block of the same 16 original columns
#pragma unroll
    for (int i = 0; i < 4; i++) {
      const int r0 = row0 + awr + i * 16 + quad * 4;
#pragma unroll
      for (int jp = 0; jp < 2; jp++) {
        const int j = jp * 2;
        const int ca = col0 + bwc + j * 16 + m16;
        const float ba = bias[ca], bg = bias[ca + 16];
        const int oc = ((col0 + bwc) >> 1) + jp * 16 + m16;
#pragma unroll
        for (int r = 0; r < 4; r++) {
          float a = acc[i][j][r] + ba;
          float g = acc[i][j + 1][r] + bg;
          float z = a / (1.f + expf(-g));
          ((ushort*)Cout)[(size_t)(r0 + r) * ldc + oc] = f2bf(z);
        }
      }
    }
  }
}

// ---------------- fused phi_k: GEMM(64 rows x 320, K=64) + FAVOR key epilogue ----------------
// data = qkv+512 (k slice); phi row trow -> qkv row trow>>3, col (trow&7)*64.
__global__ __launch_bounds__(256) void phi_k_fused(const ushort* __restrict__ data,
                                                   const ushort* __restrict__ projp,
                                                   ushort* __restrict__ out) {
  __shared__ ushort Bs[320 * 64];   // 40 KB; reused as output staging
  __shared__ ushort As[64 * 64];
  __shared__ float diag_sh[64];
  const int t0 = blockIdx.x * 64;
  const int tid = threadIdx.x;
  const int w = tid >> 6, lane = tid & 63;
  const int rl8 = lane >> 3;
  const int lc8 = ((lane & 7) ^ (rl8 & 7)) * 8;
#pragma unroll
  for (int j = 0; j < 10; j++) {
    const int rb = w * 80 + j * 8;
    async_cp16(projp + (size_t)(rb + rl8) * 64 + lc8, Bs + rb * 64);
  }
#pragma unroll
  for (int j = 0; j < 2; j++) {
    const int rb = w * 16 + j * 8;
    const int trow = t0 + rb + rl8;
    async_cp16(data + (size_t)(trow >> 3) * QKVS_ + (trow & 7) * 64 + lc8, As + rb * 64);
  }
  __syncthreads();
  {
    const int r = w * 16 + (lane >> 2);
    const int c0 = 2 * (lane & 3);
    float s = 0.f;
#pragma unroll
    for (int cc = 0; cc < 2; cc++) {
      short8 vv = *(const short8*)&As[r * 64 + ((c0 + cc) ^ (r & 7)) * 8];
      const ushort* u = (const ushort*)&vv;
#pragma unroll
      for (int j = 0; j < 8; j++) { float f = bf2f(u[j]); s += f * f; }
    }
    s += __shfl_xor(s, 1);
    s += __shfl_xor(s, 2);
    if ((lane & 3) == 0) diag_sh[r] = 0.0625f * s;
  }
  __syncthreads();
  const int l16 = lane & 15, quad = lane >> 4;
  floatx4 acc[20];
#pragma unroll
  for (int cf = 0; cf < 20; cf++) acc[cf] = (floatx4){0.f, 0.f, 0.f, 0.f};
  const int ar = w * 16 + l16;
#pragma unroll
  for (int s = 0; s < 2; s++) {
    short8 af = *(const short8*)&As[ar * 64 + ((s * 4 + quad) ^ (ar & 7)) * 8];
#pragma unroll
    for (int cf = 0; cf < 20; cf++) {
      const int br = cf * 16 + l16;
      short8 bf = *(const short8*)&Bs[br * 64 + ((s * 4 + quad) ^ (br & 7)) * 8];
      acc[cf] = __builtin_amdgcn_mfma_f32_16x16x32_bf16(af, bf, acc[cf], 0, 0, 0);
    }
  }
  const float dn = 0.35355339059327373f;
  const float ratio = 0.06131393394849658f;
  float dg[4];
#pragma unroll
  for (int r = 0; r < 4; r++) dg[r] = diag_sh[w * 16 + quad * 4 + r];
  __syncthreads();   // Bs reads done; reuse as output staging [64][320]
  ushort* ost = Bs;
#pragma unroll
  for (int r = 0; r < 4; r++) {
    const int row = w * 16 + quad * 4 + r;
#pragma unroll
    for (int cf = 0; cf < 20; cf++) {
      const int col = cf * 16 + l16;
      float val = (col < M_) ? ratio * expf(dn * acc[cf][r] - dg[r] + 1e-4f) : 0.f;
      ost[row * 320 + col] = f2bf(val);
    }
  }
  __syncthreads();
#pragma unroll
  for (int it = 0; it < 10; it++) {
    int idx = tid + it * 256;          // 2560 = 64 rows * 40 chunks
    int row = idx / 40, c8 = idx % 40;
    *(uint4*)(out + (size_t)(t0 + row) * PS_ + c8 * 8) = *(const uint4*)&ost[row * 320 + c8 * 8];
  }
}

// ---------------- ctx partials + ksum partials: MFMA over n-chunk of 512 ----------------
// grid (bh=32, mt=5, ns=NS_). part[bh][ns][mt][64m][64e] fp32; kpart[bh][ns][mt][64m].
__global__ __launch_bounds__(256) void ctx_mfma(const ushort* __restrict__ kp,
                                                const ushort* __restrict__ qkv,
                                                float* __restrict__ part,
                                                float* __restrict__ kpart) {
  __shared__ ushort kps[64][40];
  __shared__ ushort vsT[64][40];
  __shared__ float kshare[4][64];
  const int bh = blockIdx.x, mt = blockIdx.y, ns = blockIdx.z;
  const int b = bh >> 3, h = bh & 7;
  const int m0 = mt * 64;
  const int tid = threadIdx.x;
  const int w = tid >> 6, lane = tid & 63, l16 = lane & 15, quad = lane >> 4;
  const int nn = tid >> 3;
  const int a8 = tid & 7;
  const int gn = nn >> 3, jn = nn & 7;
  const int pc = ((gn ^ (a8 & 3)) << 3) | jn;
  const int km = tid & 63, kg = tid >> 6;
  floatx4 acc[4] = {};
  float ksp = 0.f;
  for (int nstep = 0; nstep < 2048 / NS_ / 32; nstep++) {
    const int n0 = ns * (2048 / NS_) + nstep * 32;
    const size_t trow = (size_t)((b * N_ + n0 + nn) * H_ + h);
    uint4 kv = *(const uint4*)(kp + trow * PS_ + m0 + a8 * 8);
    uint4 vv = *(const uint4*)(qkv + ((size_t)(b * N_ + n0 + nn)) * QKVS_ + 1024 + h * 64 + a8 * 8);
    __syncthreads();
    const ushort* ke = (const ushort*)&kv;
    const ushort* ve = (const ushort*)&vv;
#pragma unroll
    for (int j = 0; j < 8; j++) kps[a8 * 8 + j][pc] = ke[j];
#pragma unroll
    for (int j = 0; j < 8; j++) vsT[a8 * 8 + j][pc] = ve[j];
    __syncthreads();
    const int am = w * 16 + l16;
    const int apg = quad ^ ((am >> 3) & 3);
    short8 af = *(const short8*)&kps[am][apg * 8];
#pragma unroll
    for (int et = 0; et < 4; et++) {
      const int be = et * 16 + l16;
      const int bpg = quad ^ ((be >> 3) & 3);
      short8 bf = *(const short8*)&vsT[be][bpg * 8];
      acc[et] = __builtin_amdgcn_mfma_f32_16x16x32_bf16(af, bf, acc[et], 0, 0, 0);
    }
    {
      short8 kr = *(const short8*)&kps[km][kg * 8];
      const ushort* ku = (const ushort*)&kr;
#pragma unroll
      for (int j = 0; j < 8; j++) ksp += bf2f(ku[j]);
    }
  }
  float* pb = part + ((size_t)(bh * NS_ + ns) * 5 + mt) * 4096;
#pragma unroll
  for (int et = 0; et < 4; et++)
#pragma unroll
    for (int r = 0; r < 4; r++)
      pb[(w * 16 + quad * 4 + r) * 64 + et * 16 + l16] = acc[et][r];
  kshare[kg][km] = ksp;
  __syncthreads();
  if (tid < 64)
    kpart[((size_t)(bh * NS_ + ns) * 5 + mt) * 64 + tid] =
        kshare[0][tid] + kshare[1][tid] + kshare[2][tid] + kshare[3][tid];
}

// ---------------- reduce partials -> ctxb bf16 [bh][288][64] + ksum[bh][PS_] ----------------
__global__ __launch_bounds__(256) void ctx_reduce(const float* __restrict__ part,
                                                  const float* __restrict__ kpart,
                                                  ushort* __restrict__ ctxb,
                                                  float* __restrict__ ksum) {
  const int bh = blockIdx.x, mt = blockIdx.y;
  const int tid = threadIdx.x;
  for (int idx = tid; idx < 4096; idx += 256) {
    float s = 0.f;
#pragma unroll
    for (int ns = 0; ns < NS_; ns++)
      s += part[((size_t)(bh * NS_ + ns) * 5 + mt) * 4096 + idx];
    int m = mt * 64 + (idx >> 6);
    if (m < 288) ctxb[((size_t)bh * 288 + m) * 64 + (idx & 63)] = f2bf(s);
  }
  if (tid < 64) {
    float s = 0.f;
#pragma unroll
    for (int ns = 0; ns < NS_; ns++)
      s += kpart[((size_t)(bh * NS_ + ns) * 5 + mt) * 64 + tid];
    ksum[(size_t)bh * PS_ + mt * 64 + tid] = s;
  }
}

// ---------------- fused phi_q + dinv + attn_out ----------------
// grid (bh=32, nt=32). Phase A: phi features for 64 tokens of head h into LDS qs
// (never hits HBM). Phase B: o = dinv * (qs @ ctxb^T).
__global__ __launch_bounds__(256) void attn_fused(const ushort* __restrict__ qkv,
                                                  const ushort* __restrict__ projp,
                                                  const ushort* __restrict__ ctxb,
                                                  const float* __restrict__ ksum,
                                                  ushort* __restrict__ o) {
  __shared__ ushort As[64 * 64];      // q tile (swizzled chunks)
  __shared__ ushort Bs[160 * 64];     // proj half (swizzled chunks)
  __shared__ ushort qs[64][328];      // phi features, plain layout
  __shared__ ushort cs[64][40];       // ctxb^T staging
  __shared__ float ks_sh[288];
  __shared__ float diag_sh[64], dsh[64];
  const int bh = blockIdx.x, b = bh >> 3, h = bh & 7;
  const int n0 = blockIdx.y * 64;
  const int tid = threadIdx.x;
  const int w = tid >> 6, lane = tid & 63, l16 = lane & 15, quad = lane >> 4;
  const int rl8 = lane >> 3;
  const int lc8 = ((lane & 7) ^ (rl8 & 7)) * 8;
  // stage q tile: token rows n0 + w*16 + j*8 + rl8, head cols h*64
#pragma unroll
  for (int j = 0; j < 2; j++) {
    const int rb = w * 16 + j * 8;
    async_cp16(qkv + (size_t)(b * N_ + n0 + rb + rl8) * QKVS_ + h * 64 + lc8, As + rb * 64);
  }
  // stage proj half0: rows 0..159
#pragma unroll
  for (int j = 0; j < 5; j++) {
    const int rb = w * 40 + j * 8;
    async_cp16(projp + (size_t)(rb + rl8) * 64 + lc8, Bs + rb * 64);
  }
  for (int i = tid; i < 288; i += 256) ks_sh[i] = ksum[(size_t)bh * PS_ + i];
  __syncthreads();
  // diag per token row
  {
    const int r = w * 16 + (lane >> 2);
    const int c0 = 2 * (lane & 3);
    float s = 0.f;
#pragma unroll
    for (int cc = 0; cc < 2; cc++) {
      short8 vv = *(const short8*)&As[r * 64 + ((c0 + cc) ^ (r & 7)) * 8];
      const ushort* u = (const ushort*)&vv;
#pragma unroll
      for (int j = 0; j < 8; j++) { float f = bf2f(u[j]); s += f * f; }
    }
    s += __shfl_xor(s, 1);
    s += __shfl_xor(s, 2);
    if ((lane & 3) == 0) diag_sh[r] = 0.0625f * s;
  }
  __syncthreads();
  // phase A GEMM: acc[18] covers m cols 0..287
  floatx4 acc[18];
#pragma unroll
  for (int cf = 0; cf < 18; cf++) acc[cf] = (floatx4){0.f, 0.f, 0.f, 0.f};
  const int ar = w * 16 + l16;
#pragma unroll
  for (int s = 0; s < 2; s++) {
    short8 af = *(const short8*)&As[ar * 64 + ((s * 4 + quad) ^ (ar & 7)) * 8];
#pragma unroll
    for (int cf = 0; cf < 10; cf++) {
      const int br = cf * 16 + l16;
      short8 bf = *(const short8*)&Bs[br * 64 + ((s * 4 + quad) ^ (br & 7)) * 8];
      acc[cf] = __builtin_amdgcn_mfma_f32_16x16x32_bf16(af, bf, acc[cf], 0, 0, 0);
    }
  }
  __syncthreads();
  // stage proj half1: rows 160..287 into Bs rows 0..127
#pragma unroll
  for (int j = 0; j < 4; j++) {
    const int rb = w * 32 + j * 8;
    async_cp16(projp + (size_t)(160 + rb + rl8) * 64 + lc8, Bs + rb * 64);
  }
  __syncthreads();
#pragma unroll
  for (int s = 0; s < 2; s++) {
    short8 af = *(const short8*)&As[ar * 64 + ((s * 4 + quad) ^ (ar & 7)) * 8];
#pragma unroll
    for (int cf = 10; cf < 18; cf++) {
      const int br = (cf - 10) * 16 + l16;
      short8 bf = *(const short8*)&Bs[br * 64 + ((s * 4 + quad) ^ (br & 7)) * 8];
      acc[cf] = __builtin_amdgcn_mfma_f32_16x16x32_bf16(af, bf, acc[cf], 0, 0, 0);
    }
  }
  // FAVOR query epilogue -> qs (LDS), dinv -> dsh
  const float dn = 0.35355339059327373f;
  const float ratio = 0.06131393394849658f;
#pragma unroll
  for (int r = 0; r < 4; r++) {
    const int row = w * 16 + quad * 4 + r;
    const float dg = diag_sh[row];
    float mx = -1e30f;
#pragma unroll
    for (int cf = 0; cf < 18; cf++) {
      const int col = cf * 16 + l16;
      if (col < M_) mx = fmaxf(mx, dn * acc[cf][r]);
    }
    mx = fmaxf(mx, __shfl_xor(mx, 1));
    mx = fmaxf(mx, __shfl_xor(mx, 2));
    mx = fmaxf(mx, __shfl_xor(mx, 4));
    mx = fmaxf(mx, __shfl_xor(mx, 8));
    float dacc = 0.f;
#pragma unroll
    for (int cf = 0; cf < 18; cf++) {
      const int col = cf * 16 + l16;
      float val = (col < M_) ? ratio * (expf(dn * acc[cf][r] - dg - mx) + 1e-4f) : 0.f;
      qs[row][col] = f2bf(val);
      dacc += val * ks_sh[col];
    }
    dacc += __shfl_xor(dacc, 1);
    dacc += __shfl_xor(dacc, 2);
    dacc += __shfl_xor(dacc, 4);
    dacc += __shfl_xor(dacc, 8);
    if (l16 == 0) dsh[row] = 1.f / (dacc + 1e-8f);
  }
  __syncthreads();
  // phase B: o[n][e] = sum_m qs[n][m] * ctxb[m][e]
  const int cm = tid >> 3, ca8 = tid & 7;
  const int gm = cm >> 3, jm = cm & 7;
  const int pcc = ((gm ^ (ca8 & 3)) << 3) | jm;
  floatx4 acc2[4] = {};
  for (int m0 = 0; m0 < 288; m0 += 32) {
    uint4 cv = *(const uint4*)(ctxb + ((size_t)bh * 288 + m0 + cm) * 64 + ca8 * 8);
    __syncthreads();
    const ushort* ce = (const ushort*)&cv;
#pragma unroll
    for (int j = 0; j < 8; j++) cs[ca8 * 8 + j][pcc] = ce[j];
    __syncthreads();
    short8 af = *(const short8*)&qs[w * 16 + l16][m0 + quad * 8];
#pragma unroll
    for (int et = 0; et < 4; et++) {
      const int be = et * 16 + l16;
      const int bpg = quad ^ ((be >> 3) & 3);
      short8 bf = *(const short8*)&cs[be][bpg * 8];
      acc2[et] = __builtin_amdgcn_mfma_f32_16x16x32_bf16(af, bf, acc2[et], 0, 0, 0);
    }
  }
#pragma unroll
  for (int r = 0; r < 4; r++) {
    const int nl = w * 16 + quad * 4 + r;
    const int n = n0 + nl;
    const float di = dsh[nl];
#pragma unroll
    for (int et = 0; et < 4; et++)
      o[((size_t)(b * N_ + n)) * 512 + h * 64 + et * 16 + l16] = f2bf(acc2[et][r] * di);
  }
}

// ---------------- depthwise conv K=31, pad 15, + bias + silu; bf16 in/out ----------------
#define TN_ 16
__global__ __launch_bounds__(256) void dwconv_kernel(const ushort* __restrict__ x,
                                                     const float* __restrict__ w,
                                                     const float* __restrict__ bias,
                                                     ushort* __restrict__ out) {
  const int bid = blockIdx.x;
  const int cb = bid & 3;
  const int nb = (bid >> 2) & 127;
  const int b  = bid >> 9;
  const int c = cb * 256 + threadIdx.x;
  const int n0 = nb * TN_;
  float win[TN_ + 30];
#pragma unroll
  for (int i = 0; i < TN_ + 30; i++) {
    int nn = n0 + i - 15;
    win[i] = (nn >= 0 && nn < N_) ? bf2f(x[(size_t)(b * N_ + nn) * INNER_ + c]) : 0.f;
  }
  float wc[31];
#pragma unroll
  for (int kk = 0; kk < 31; kk++) wc[kk] = w[c * 31 + kk];
  const float bsv = bias[c];
#pragma unroll
  for (int j = 0; j < TN_; j++) {
    float acc = bsv;
#pragma unroll
    for (int kk = 0; kk < 31; kk++) acc += win[j + kk] * wc[kk];
    acc = acc / (1.f + expf(-acc));
    out[(size_t)(b * N_ + n0 + j) * INNER_ + c] = f2bf(acc);
  }
}

// ---------------- host ----------------
extern "C" void kernel_launch(void* const* d_in, const int* in_sizes, int n_in,
                              void* d_out, int out_size, void* d_ws, size_t ws_size,
                              hipStream_t stream) {
  const float* in_x  = (const float*)d_in[0];
  const float* ln1_g = (const float*)d_in[1];
  const float* ln1_b = (const float*)d_in[2];
  const float* wq    = (const float*)d_in[3];
  const float* bq    = (const float*)d_in[4];
  const float* wk    = (const float*)d_in[5];
  const float* bk    = (const float*)d_in[6];
  const float* wv    = (const float*)d_in[7];
  const float* bv    = (const float*)d_in[8];
  const float* wo    = (const float*)d_in[9];
  const float* bo    = (const float*)d_in[10];
  const float* proj  = (const float*)d_in[11];
  const float* ln2_g = (const float*)d_in[12];
  const float* ln2_b = (const float*)d_in[13];
  const float* pw1_w = (const float*)d_in[14];
  const float* pw1_b = (const float*)d_in[15];
  const float* dw_w  = (const float*)d_in[16];
  const float* dw_b  = (const float*)d_in[17];
  const float* pw2_w = (const float*)d_in[18];
  const float* pw2_b = (const float*)d_in[19];

  char* cur = (char*)d_ws;
  auto alloc = [&](size_t bytes) { char* p = cur; cur += (bytes + 255) & ~(size_t)255; return p; };
  float*  x    = (float*)alloc((size_t)T_ * D_ * 4);
  ushort* p    = (ushort*)alloc((size_t)ROWS_ * PS_ * 2);          // kp; glu+conv alias
  float*  part = (float*)alloc((size_t)32 * NS_ * 5 * 4096 * 4);
  float*  kpart= (float*)alloc((size_t)32 * NS_ * 5 * 64 * 4);
  ushort* ctxb = (ushort*)alloc((size_t)32 * 288 * 64 * 2);
  float*  ksum = (float*)alloc((size_t)32 * PS_ * 4);
  ushort* h    = (ushort*)alloc((size_t)T_ * D_ * 2);
  ushort* qkv  = (ushort*)alloc((size_t)T_ * QKVS_ * 2);
  ushort* obuf = (ushort*)alloc((size_t)T_ * D_ * 2);
  ushort* wqkv_b = (ushort*)alloc((size_t)L_LAYERS * QKVS_ * 512 * 2);
  float*  bqkv   = (float*)alloc((size_t)L_LAYERS * QKVS_ * 4);
  ushort* wo_b = (ushort*)alloc((size_t)L_LAYERS * D_ * D_ * 2);
  ushort* pjp  = (ushort*)alloc((size_t)L_LAYERS * 320 * 64 * 2);
  ushort* p1_b = (ushort*)alloc((size_t)L_LAYERS * 2048 * D_ * 2);
  float*  pb1  = (float*)alloc((size_t)L_LAYERS * 2048 * 4);
  ushort* p2_b = (ushort*)alloc((size_t)L_LAYERS * D_ * INNER_ * 2);
  ushort* glu  = p;                                   // T*1024 bf16 (dead kp region)
  ushort* conv = p + (size_t)T_ * INNER_;

  pack_qkv_w<<<(L_LAYERS * 512 * 128 + 255) / 256, 256, 0, stream>>>((const float4*)wq, wqkv_b, 0);
  pack_qkv_w<<<(L_LAYERS * 512 * 128 + 255) / 256, 256, 0, stream>>>((const float4*)wk, wqkv_b, 512);
  pack_qkv_w<<<(L_LAYERS * 512 * 128 + 255) / 256, 256, 0, stream>>>((const float4*)wv, wqkv_b, 1024);
  pack_qkv_b<<<(L_LAYERS * QKVS_ + 255) / 256, 256, 0, stream>>>(bq, bk, bv, bqkv);
  pad_proj<<<(L_LAYERS * 320 * 64 + 255) / 256, 256, 0, stream>>>(proj, pjp);
  pack_pw1_w<<<(L_LAYERS * 2048 * 128 + 255) / 256, 256, 0, stream>>>((const float4*)pw1_w, p1_b);
  pack_pw1_b<<<(L_LAYERS * 2048 + 255) / 256, 256, 0, stream>>>(pw1_b, pb1);
  {
    int n4 = L_LAYERS * D_ * D_ / 4;
    f2bf4_kernel<<<(n4 + 255) / 256, 256, 0, stream>>>((const float4*)wo, wo_b, n4);
    n4 = L_LAYERS * D_ * INNER_ / 4;
    f2bf4_kernel<<<(n4 + 255) / 256, 256, 0, stream>>>((const float4*)pw2_w, p2_b, n4);
  }

  for (int l = 0; l < L_LAYERS; l++) {
    const ushort* wqkvl = wqkv_b + (size_t)l * QKVS_ * 512;
    const ushort* wol = wo_b + (size_t)l * D_ * D_;
    const ushort* pjl = pjp + (size_t)l * 320 * 64;
    const ushort* p1l = p1_b + (size_t)l * 2048 * D_;
    const ushort* p2l = p2_b + (size_t)l * D_ * INNER_;
    const float*  dwl = dw_w + (size_t)l * INNER_ * 31;
    const float*  xin = (l == 0) ? in_x : x;
    float* xout = (l == L_LAYERS - 1) ? (float*)d_out : x;

    ln_kernel<<<T_, 256, 0, stream>>>(xin, ln1_g + l * D_, ln1_b + l * D_, h);
    gemm_mfma<false, true, 0><<<dim3(T_ / 128, QKVS_ / 128), 256, 0, stream>>>(
        h, wqkvl, bqkv + (size_t)l * QKVS_, nullptr, qkv, D_, QKVS_);
    phi_k_fused<<<ROWS_ / 64, 256, 0, stream>>>(qkv + 512, pjl, p);
    ctx_mfma<<<dim3(32, 5, NS_), 256, 0, stream>>>(p, qkv, part, kpart);
    ctx_reduce<<<dim3(32, 5), 256, 0, stream>>>(part, kpart, ctxb, ksum);
    attn_fused<<<dim3(32, 32), 256, 0, stream>>>(qkv, pjl, ctxb, ksum, obuf);
    gemm_mfma<true, false, 0><<<dim3(T_ / 128, 4), 256, 0, stream>>>(
        obuf, wol, bo + l * D_, xin, x, D_, D_);
    ln_kernel<<<T_, 256, 0, stream>>>(x, ln2_g + l * D_, ln2_b + l * D_, h);
    // pw1 + GLU fused (interleaved weights) -> glu buffer [T][1024]
    gemm_mfma<false, true, 1><<<dim3(T_ / 128, 16), 256, 0, stream>>>(
        h, p1l, pb1 + (size_t)l * 2048, nullptr, glu, D_, INNER_);
    dwconv_kernel<<<B_ * (N_ / TN_) * 4, 256, 0, stream>>>(glu, dwl, dw_b + l * INNER_, conv);
    gemm_mfma<true, false, 0><<<dim3(T_ / 128, 4), 256, 0, stream>>>(
        conv, p2l, pw2_b + l * D_, x, xout, INNER_, D_);
  }
}

// Round 7
// 1386.293 us; speedup vs baseline: 6.7173x; 1.0208x over previous
//
#include <hip/hip_runtime.h>

// PCmer forward: bf16-MFMA; phi_k fused INTO ctx (kp never hits HBM); phi_q+dinv+attn_out fused;
// GLU fused into pw1 (interleaved weights); fused QKV; ksum fused into ctx.
// L=6, B=4, N=2048, D=512, H=8, DH=64, ID=512, M=266, INNER=1024, K=31.

#define L_LAYERS 6
#define B_ 4
#define N_ 2048
#define D_ 512
#define H_ 8
#define DH_ 64
#define M_ 266
#define INNER_ 1024
#define T_ 8192            // B*N tokens
#define ROWS_ 65536        // B*N*H rows for phi
#define PS_ 320            // padded m stride (zeros in [266,320))
#define QKVS_ 1536         // qkv row stride
#define NS_ 4              // ctx n-splits

typedef __attribute__((ext_vector_type(8))) short short8;
typedef __attribute__((ext_vector_type(4))) float floatx4;

__device__ __forceinline__ ushort f2bf(float f) {
  union { float f; uint u; } v; v.f = f;
  uint r = v.u + 0x7fffu + ((v.u >> 16) & 1u);
  return (ushort)(r >> 16);
}
__device__ __forceinline__ float bf2f(ushort u) {
  union { uint u; float f; } v; v.u = ((uint)u) << 16;
  return v.f;
}
__device__ __forceinline__ float wave_sum(float v) {
#pragma unroll
  for (int m = 1; m < 64; m <<= 1) v += __shfl_xor(v, m);
  return v;
}
// async global->LDS, 16B per lane; dest = wave-uniform base + lane*16 (src per-lane)
__device__ __forceinline__ void async_cp16(const void* g, void* l) {
  __builtin_amdgcn_global_load_lds(
      (const __attribute__((address_space(1))) void*)g,
      (__attribute__((address_space(3))) void*)l, 16, 0, 0);
}

// ---------------- weight packing ----------------
__global__ void f2bf4_kernel(const float4* __restrict__ in, ushort* __restrict__ out, int n4) {
  int i = blockIdx.x * 256 + threadIdx.x;
  if (i < n4) {
    float4 v = in[i];
    ushort4 r;
    r.x = f2bf(v.x); r.y = f2bf(v.y); r.z = f2bf(v.z); r.w = f2bf(v.w);
    *(ushort4*)(out + (size_t)i * 4) = r;
  }
}
__global__ void pack_qkv_w(const float4* __restrict__ src, ushort* __restrict__ dst, int off) {
  int i = blockIdx.x * 256 + threadIdx.x;   // L*512*128
  if (i >= L_LAYERS * 512 * 128) return;
  int l = i >> 16;
  int rem = i & 65535;
  int row = rem >> 7, c4 = rem & 127;
  float4 v = src[i];
  ushort4 r;
  r.x = f2bf(v.x); r.y = f2bf(v.y); r.z = f2bf(v.z); r.w = f2bf(v.w);
  *(ushort4*)(dst + ((size_t)l * QKVS_ + off + row) * 512 + c4 * 4) = r;
}
__global__ void pack_qkv_b(const float* __restrict__ bq, const float* __restrict__ bk,
                           const float* __restrict__ bv, float* __restrict__ dst) {
  int i = blockIdx.x * 256 + threadIdx.x;   // L*1536
  if (i >= L_LAYERS * QKVS_) return;
  int l = i / QKVS_, c = i % QKVS_;
  dst[i] = c < 512 ? bq[l * 512 + c] : (c < 1024 ? bk[l * 512 + c - 512] : bv[l * 512 + c - 1024]);
}
__global__ void pad_proj(const float* __restrict__ proj, ushort* __restrict__ dst) {
  int i = blockIdx.x * 256 + threadIdx.x;   // L*320*64
  if (i >= L_LAYERS * 320 * 64) return;
  int l = i / (320 * 64), rem = i % (320 * 64), m = rem >> 6, kk = rem & 63;
  dst[i] = (m < M_) ? f2bf(proj[((size_t)l * M_ + m) * 64 + kk]) : (ushort)0;
}
// pw1 interleave: out col c' = 32b+16s+j16 -> src row s*1024 + 16b + j16
__global__ void pack_pw1_w(const float4* __restrict__ src, ushort* __restrict__ dst) {
  int i = blockIdx.x * 256 + threadIdx.x;   // L*2048*128
  if (i >= L_LAYERS * 2048 * 128) return;
  int l = i >> 18;
  int rem = i & 262143;
  int cp = rem >> 7, c4 = rem & 127;
  int s = (cp >> 4) & 1;
  int srow = ((cp >> 5) << 4) + (cp & 15) + s * 1024;
  float4 v = src[((size_t)l * 2048 + srow) * 128 + c4];
  ushort4 r;
  r.x = f2bf(v.x); r.y = f2bf(v.y); r.z = f2bf(v.z); r.w = f2bf(v.w);
  *(ushort4*)(dst + ((size_t)l * 2048 + cp) * 512 + c4 * 4) = r;
}
__global__ void pack_pw1_b(const float* __restrict__ src, float* __restrict__ dst) {
  int i = blockIdx.x * 256 + threadIdx.x;   // L*2048
  if (i >= L_LAYERS * 2048) return;
  int l = i >> 11, cp = i & 2047;
  int s = (cp >> 4) & 1;
  int srow = ((cp >> 5) << 4) + (cp & 15) + s * 1024;
  dst[i] = src[l * 2048 + srow];
}

// ---------------- layernorm (block per token, D=512), bf16 out ----------------
__global__ __launch_bounds__(256) void ln_kernel(const float* __restrict__ x,
                                                 const float* __restrict__ g,
                                                 const float* __restrict__ b,
                                                 ushort* __restrict__ out) {
  const int t = blockIdx.x;
  const int tid = threadIdx.x;
  const float* row = x + (size_t)t * D_;
  float v0 = row[tid], v1 = row[tid + 256];
  float s1 = v0 + v1;
  float s2 = v0 * v0 + v1 * v1;
  s1 = wave_sum(s1);
  s2 = wave_sum(s2);
  __shared__ float sh1[4], sh2[4];
  int w = tid >> 6;
  if ((tid & 63) == 0) { sh1[w] = s1; sh2[w] = s2; }
  __syncthreads();
  s1 = sh1[0] + sh1[1] + sh1[2] + sh1[3];
  s2 = sh2[0] + sh2[1] + sh2[2] + sh2[3];
  float mu = s1 * (1.f / D_);
  float var = s2 * (1.f / D_) - mu * mu;
  float rs = rsqrtf(var + 1e-5f);
  out[(size_t)t * D_ + tid]       = f2bf((v0 - mu) * rs * g[tid] + b[tid]);
  out[(size_t)t * D_ + tid + 256] = f2bf((v1 - mu) * rs * g[tid + 256] + b[tid + 256]);
}

// ---------------- bf16 MFMA GEMM (global_load_lds staging, XOR-swizzled LDS) -----------------
template <bool HAS_RES, bool OUT_BF16, int ACT>
__global__ __launch_bounds__(256) void gemm_mfma(const ushort* __restrict__ A,
                                                 const ushort* __restrict__ W,
                                                 const float* __restrict__ bias,
                                                 const float* __restrict__ res,
                                                 void* __restrict__ Cout,
                                                 int K, int ldc) {
  __shared__ ushort As[128 * 32];
  __shared__ ushort Bs[128 * 32];
  const int tid = threadIdx.x;
  const int w = tid >> 6, lane = tid & 63;
  const int row0 = blockIdx.x * 128, col0 = blockIdx.y * 128;
  const int rl = lane >> 2;
  const int lc = ((lane & 3) ^ ((lane >> 3) & 3)) * 8;
  const ushort* gA0 = A + (size_t)(row0 + w * 32 + rl) * K + lc;
  const ushort* gA1 = gA0 + (size_t)16 * K;
  const ushort* gB0 = W + (size_t)(col0 + w * 32 + rl) * K + lc;
  const ushort* gB1 = gB0 + (size_t)16 * K;
  ushort* lA = As + w * 1024;
  ushort* lB = Bs + w * 1024;
  const int m16 = lane & 15, quad = lane >> 4;
  const int awr = (w >> 1) * 64, bwc = (w & 1) * 64;
  floatx4 acc[4][4] = {};
  for (int k0 = 0; k0 < K; k0 += 32) {
    __syncthreads();
    async_cp16(gA0 + k0, lA);
    async_cp16(gA1 + k0, lA + 512);
    async_cp16(gB0 + k0, lB);
    async_cp16(gB1 + k0, lB + 512);
    __syncthreads();
    short8 af[4], bfr[4];
#pragma unroll
    for (int i = 0; i < 4; i++) {
      int r = awr + i * 16 + m16;
      af[i] = *(const short8*)&As[r * 32 + (quad ^ ((r >> 1) & 3)) * 8];
    }
#pragma unroll
    for (int j = 0; j < 4; j++) {
      int r = bwc + j * 16 + m16;
      bfr[j] = *(const short8*)&Bs[r * 32 + (quad ^ ((r >> 1) & 3)) * 8];
    }
#pragma unroll
    for (int i = 0; i < 4; i++)
#pragma unroll
      for (int j = 0; j < 4; j++)
        acc[i][j] = __builtin_amdgcn_mfma_f32_16x16x32_bf16(af[i], bfr[j], acc[i][j], 0, 0, 0);
  }
  if (ACT == 0) {
#pragma unroll
    for (int i = 0; i < 4; i++) {
      const int r0 = row0 + awr + i * 16 + quad * 4;
#pragma unroll
      for (int j = 0; j < 4; j++) {
        const int c = col0 + bwc + j * 16 + m16;
        const float bv = bias[c];
#pragma unroll
        for (int r = 0; r < 4; r++) {
          float vv = acc[i][j][r] + bv;
          if (HAS_RES) vv += res[(size_t)(r0 + r) * ldc + c];
          if (OUT_BF16) ((ushort*)Cout)[(size_t)(r0 + r) * ldc + c] = f2bf(vv);
          else          ((float*)Cout)[(size_t)(r0 + r) * ldc + c] = vv;
        }
      }
    }
  } else {
    // GLU epilogue on interleaved columns: z = (a+ba)*sigmoid(g+bg)
#pragma unroll
    for (int i = 0; i < 4; i++) {
      const int r0 = row0 + awr + i * 16 + quad * 4;
#pragma unroll
      for (int jp = 0; jp < 2; jp++) {
        const int j = jp * 2;
        const int ca = col0 + bwc + j * 16 + m16;
        const float ba = bias[ca], bg = bias[ca + 16];
        const int oc = ((col0 + bwc) >> 1) + jp * 16 + m16;
#pragma unroll
        for (int r = 0; r < 4; r++) {
          float a = acc[i][j][r] + ba;
          float g = acc[i][j + 1][r] + bg;
          float z = a / (1.f + expf(-g));
          ((ushort*)Cout)[(size_t)(r0 + r) * ldc + oc] = f2bf(z);
        }
      }
    }
  }
}

// ---------------- ctx with phi_k fused: kp computed in-LDS, never hits HBM ----------------
// grid (bh=32, mt=5, ns=NS_). For each 32-token chunk: stage raw k-tile, MFMA vs LDS proj
// slice, FAVOR key epilogue in-register -> swizzled kps LDS; then ctx MFMA + ksum partials.
__global__ __launch_bounds__(256) void ctx_phi_mfma(const ushort* __restrict__ qkv,
                                                    const ushort* __restrict__ projp,
                                                    float* __restrict__ part,
                                                    float* __restrict__ kpart) {
  __shared__ ushort projs[64 * 64];  // proj rows m0..m0+63, XOR-chunk layout
  __shared__ ushort kts[32 * 64];    // raw k tile, XOR-chunk layout
  __shared__ ushort kps[64][40];     // phi^T [m][n swizzled]
  __shared__ ushort vsT[64][40];     // v^T  [e][n swizzled]
  __shared__ float diag_sh[32];
  __shared__ float kshare[4][64];
  const int bh = blockIdx.x, mt = blockIdx.y, ns = blockIdx.z;
  const int b = bh >> 3, h = bh & 7;
  const int m0 = mt * 64;
  const int tid = threadIdx.x;
  const int w = tid >> 6, lane = tid & 63, l16 = lane & 15, quad = lane >> 4;
  const int rl8 = lane >> 3;
  const int lc8 = ((lane & 7) ^ (rl8 & 7)) * 8;
  // stage proj slice once (rows m0..m0+63)
#pragma unroll
  for (int j = 0; j < 2; j++) {
    const int rb = w * 16 + j * 8;
    async_cp16(projp + (size_t)(m0 + rb + rl8) * 64 + lc8, projs + rb * 64);
  }
  // v scatter mapping (n = nn, e-octet a8)
  const int nn = tid >> 3;
  const int a8 = tid & 7;
  const int gn = nn >> 3, jn = nn & 7;
  const int pc = ((gn ^ (a8 & 3)) << 3) | jn;
  const int km = tid & 63, kg = tid >> 6;  // ksum mapping
  const float dn = 0.35355339059327373f;   // 64^-0.25
  const float ratio = 0.06131393394849658f;
  floatx4 acc[4] = {};
  float ksp = 0.f;
  for (int nstep = 0; nstep < 2048 / NS_ / 32; nstep++) {
    const int n0 = ns * (2048 / NS_) + nstep * 32;
    // stage raw k tile (32 tokens x 64 dh): wave w stages rows w*8..w*8+7
    {
      const int rb = w * 8;
      async_cp16(qkv + (size_t)(b * N_ + n0 + rb + rl8) * QKVS_ + 512 + h * 64 + lc8,
                 kts + rb * 64);
    }
    uint4 vv = *(const uint4*)(qkv + ((size_t)(b * N_ + n0 + nn)) * QKVS_ + 1024 + h * 64 + a8 * 8);
    __syncthreads();   // [A] prev-iter LDS reads done; kts staged (barrier drains vmcnt)
    // diag per token: 8 lanes per row
    {
      const int r = tid >> 3;        // 0..31
      const int c = tid & 7;
      short8 kv8 = *(const short8*)&kts[r * 64 + c * 8];
      const ushort* u = (const ushort*)&kv8;
      float s = 0.f;
#pragma unroll
      for (int j = 0; j < 8; j++) { float f = bf2f(u[j]); s += f * f; }
      s += __shfl_xor(s, 1);
      s += __shfl_xor(s, 2);
      s += __shfl_xor(s, 4);
      if ((tid & 7) == 0) diag_sh[r] = 0.0625f * s;   // 0.5*dn^2
    }
    // v scatter into vsT
    {
      const ushort* ve = (const ushort*)&vv;
#pragma unroll
      for (int j = 0; j < 8; j++) vsT[a8 * 8 + j][pc] = ve[j];
    }
    __syncthreads();   // [B] diag + vsT + kts visible
    // phi MFMA: out[m=64][n=32]; wave w -> m rows w*16..w*16+15
    floatx4 pacc[2] = {};
#pragma unroll
    for (int s = 0; s < 2; s++) {
      const int ar = w * 16 + l16;
      short8 af = *(const short8*)&projs[ar * 64 + ((s * 4 + quad) ^ (ar & 7)) * 8];
#pragma unroll
      for (int nj = 0; nj < 2; nj++) {
        const int br = nj * 16 + l16;
        short8 bf = *(const short8*)&kts[br * 64 + ((s * 4 + quad) ^ (br & 7)) * 8];
        pacc[nj] = __builtin_amdgcn_mfma_f32_16x16x32_bf16(af, bf, pacc[nj], 0, 0, 0);
      }
    }
    // FAVOR key epilogue -> kps (swizzled scatter)
#pragma unroll
    for (int nj = 0; nj < 2; nj++) {
      const int n = nj * 16 + l16;
      const float dgn = diag_sh[n];
#pragma unroll
      for (int r = 0; r < 4; r++) {
        const int m = w * 16 + quad * 4 + r;
        float val = (m0 + m < M_) ? ratio * expf(dn * pacc[nj][r] - dgn + 1e-4f) : 0.f;
        kps[m][(((n >> 3) ^ ((m >> 3) & 3)) << 3) | (n & 7)] = f2bf(val);
      }
    }
    __syncthreads();   // [C] kps ready
    // ctx MFMA
    const int am = w * 16 + l16;
    const int apg = quad ^ ((am >> 3) & 3);
    short8 af = *(const short8*)&kps[am][apg * 8];
#pragma unroll
    for (int et = 0; et < 4; et++) {
      const int be = et * 16 + l16;
      const int bpg = quad ^ ((be >> 3) & 3);
      short8 bf = *(const short8*)&vsT[be][bpg * 8];
      acc[et] = __builtin_amdgcn_mfma_f32_16x16x32_bf16(af, bf, acc[et], 0, 0, 0);
    }
    // ksum partial (row km, physical chunk kg; permutation within row is sum-invariant)
    {
      short8 kr = *(const short8*)&kps[km][kg * 8];
      const ushort* ku = (const ushort*)&kr;
#pragma unroll
      for (int j = 0; j < 8; j++) ksp += bf2f(ku[j]);
    }
  }
  float* pb = part + ((size_t)(bh * NS_ + ns) * 5 + mt) * 4096;
#pragma unroll
  for (int et = 0; et < 4; et++)
#pragma unroll
    for (int r = 0; r < 4; r++)
      pb[(w * 16 + quad * 4 + r) * 64 + et * 16 + l16] = acc[et][r];
  kshare[kg][km] = ksp;
  __syncthreads();
  if (tid < 64)
    kpart[((size_t)(bh * NS_ + ns) * 5 + mt) * 64 + tid] =
        kshare[0][tid] + kshare[1][tid] + kshare[2][tid] + kshare[3][tid];
}

// ---------------- reduce partials -> ctxb bf16 [bh][288][64] + ksum[bh][PS_] ----------------
__global__ __launch_bounds__(256) void ctx_reduce(const float* __restrict__ part,
                                                  const float* __restrict__ kpart,
                                                  ushort* __restrict__ ctxb,
                                                  float* __restrict__ ksum) {
  const int bh = blockIdx.x, mt = blockIdx.y;
  const int tid = threadIdx.x;
  for (int idx = tid; idx < 4096; idx += 256) {
    float s = 0.f;
#pragma unroll
    for (int ns = 0; ns < NS_; ns++)
      s += part[((size_t)(bh * NS_ + ns) * 5 + mt) * 4096 + idx];
    int m = mt * 64 + (idx >> 6);
    if (m < 288) ctxb[((size_t)bh * 288 + m) * 64 + (idx & 63)] = f2bf(s);
  }
  if (tid < 64) {
    float s = 0.f;
#pragma unroll
    for (int ns = 0; ns < NS_; ns++)
      s += kpart[((size_t)(bh * NS_ + ns) * 5 + mt) * 64 + tid];
    ksum[(size_t)bh * PS_ + mt * 64 + tid] = s;
  }
}

// ---------------- fused phi_q + dinv + attn_out ----------------
__global__ __launch_bounds__(256) void attn_fused(const ushort* __restrict__ qkv,
                                                  const ushort* __restrict__ projp,
                                                  const ushort* __restrict__ ctxb,
                                                  const float* __restrict__ ksum,
                                                  ushort* __restrict__ o) {
  __shared__ ushort As[64 * 64];      // q tile (swizzled chunks)
  __shared__ ushort Bs[160 * 64];     // proj half (swizzled chunks)
  __shared__ ushort qs[64][328];      // phi features, plain layout
  __shared__ ushort cs[64][40];       // ctxb^T staging
  __shared__ float ks_sh[288];
  __shared__ float diag_sh[64], dsh[64];
  const int bh = blockIdx.x, b = bh >> 3, h = bh & 7;
  const int n0 = blockIdx.y * 64;
  const int tid = threadIdx.x;
  const int w = tid >> 6, lane = tid & 63, l16 = lane & 15, quad = lane >> 4;
  const int rl8 = lane >> 3;
  const int lc8 = ((lane & 7) ^ (rl8 & 7)) * 8;
#pragma unroll
  for (int j = 0; j < 2; j++) {
    const int rb = w * 16 + j * 8;
    async_cp16(qkv + (size_t)(b * N_ + n0 + rb + rl8) * QKVS_ + h * 64 + lc8, As + rb * 64);
  }
#pragma unroll
  for (int j = 0; j < 5; j++) {
    const int rb = w * 40 + j * 8;
    async_cp16(projp + (size_t)(rb + rl8) * 64 + lc8, Bs + rb * 64);
  }
  for (int i = tid; i < 288; i += 256) ks_sh[i] = ksum[(size_t)bh * PS_ + i];
  __syncthreads();
  {
    const int r = w * 16 + (lane >> 2);
    const int c0 = 2 * (lane & 3);
    float s = 0.f;
#pragma unroll
    for (int cc = 0; cc < 2; cc++) {
      short8 vv = *(const short8*)&As[r * 64 + ((c0 + cc) ^ (r & 7)) * 8];
      const ushort* u = (const ushort*)&vv;
#pragma unroll
      for (int j = 0; j < 8; j++) { float f = bf2f(u[j]); s += f * f; }
    }
    s += __shfl_xor(s, 1);
    s += __shfl_xor(s, 2);
    if ((lane & 3) == 0) diag_sh[r] = 0.0625f * s;
  }
  __syncthreads();
  floatx4 acc[18];
#pragma unroll
  for (int cf = 0; cf < 18; cf++) acc[cf] = (floatx4){0.f, 0.f, 0.f, 0.f};
  const int ar = w * 16 + l16;
#pragma unroll
  for (int s = 0; s < 2; s++) {
    short8 af = *(const short8*)&As[ar * 64 + ((s * 4 + quad) ^ (ar & 7)) * 8];
#pragma unroll
    for (int cf = 0; cf < 10; cf++) {
      const int br = cf * 16 + l16;
      short8 bf = *(const short8*)&Bs[br * 64 + ((s * 4 + quad) ^ (br & 7)) * 8];
      acc[cf] = __builtin_amdgcn_mfma_f32_16x16x32_bf16(af, bf, acc[cf], 0, 0, 0);
    }
  }
  __syncthreads();
#pragma unroll
  for (int j = 0; j < 4; j++) {
    const int rb = w * 32 + j * 8;
    async_cp16(projp + (size_t)(160 + rb + rl8) * 64 + lc8, Bs + rb * 64);
  }
  __syncthreads();
#pragma unroll
  for (int s = 0; s < 2; s++) {
    short8 af = *(const short8*)&As[ar * 64 + ((s * 4 + quad) ^ (ar & 7)) * 8];
#pragma unroll
    for (int cf = 10; cf < 18; cf++) {
      const int br = (cf - 10) * 16 + l16;
      short8 bf = *(const short8*)&Bs[br * 64 + ((s * 4 + quad) ^ (br & 7)) * 8];
      acc[cf] = __builtin_amdgcn_mfma_f32_16x16x32_bf16(af, bf, acc[cf], 0, 0, 0);
    }
  }
  const float dn = 0.35355339059327373f;
  const float ratio = 0.06131393394849658f;
#pragma unroll
  for (int r = 0; r < 4; r++) {
    const int row = w * 16 + quad * 4 + r;
    const float dg = diag_sh[row];
    float mx = -1e30f;
#pragma unroll
    for (int cf = 0; cf < 18; cf++) {
      const int col = cf * 16 + l16;
      if (col < M_) mx = fmaxf(mx, dn * acc[cf][r]);
    }
    mx = fmaxf(mx, __shfl_xor(mx, 1));
    mx = fmaxf(mx, __shfl_xor(mx, 2));
    mx = fmaxf(mx, __shfl_xor(mx, 4));
    mx = fmaxf(mx, __shfl_xor(mx, 8));
    float dacc = 0.f;
#pragma unroll
    for (int cf = 0; cf < 18; cf++) {
      const int col = cf * 16 + l16;
      float val = (col < M_) ? ratio * (expf(dn * acc[cf][r] - dg - mx) + 1e-4f) : 0.f;
      qs[row][col] = f2bf(val);
      dacc += val * ks_sh[col];
    }
    dacc += __shfl_xor(dacc, 1);
    dacc += __shfl_xor(dacc, 2);
    dacc += __shfl_xor(dacc, 4);
    dacc += __shfl_xor(dacc, 8);
    if (l16 == 0) dsh[row] = 1.f / (dacc + 1e-8f);
  }
  __syncthreads();
  const int cm = tid >> 3, ca8 = tid & 7;
  const int gm = cm >> 3, jm = cm & 7;
  const int pcc = ((gm ^ (ca8 & 3)) << 3) | jm;
  floatx4 acc2[4] = {};
  for (int m0 = 0; m0 < 288; m0 += 32) {
    uint4 cv = *(const uint4*)(ctxb + ((size_t)bh * 288 + m0 + cm) * 64 + ca8 * 8);
    __syncthreads();
    const ushort* ce = (const ushort*)&cv;
#pragma unroll
    for (int j = 0; j < 8; j++) cs[ca8 * 8 + j][pcc] = ce[j];
    __syncthreads();
    short8 af = *(const short8*)&qs[w * 16 + l16][m0 + quad * 8];
#pragma unroll
    for (int et = 0; et < 4; et++) {
      const int be = et * 16 + l16;
      const int bpg = quad ^ ((be >> 3) & 3);
      short8 bf = *(const short8*)&cs[be][bpg * 8];
      acc2[et] = __builtin_amdgcn_mfma_f32_16x16x32_bf16(af, bf, acc2[et], 0, 0, 0);
    }
  }
#pragma unroll
  for (int r = 0; r < 4; r++) {
    const int nl = w * 16 + quad * 4 + r;
    const int n = n0 + nl;
    const float di = dsh[nl];
#pragma unroll
    for (int et = 0; et < 4; et++)
      o[((size_t)(b * N_ + n)) * 512 + h * 64 + et * 16 + l16] = f2bf(acc2[et][r] * di);
  }
}

// ---------------- depthwise conv K=31, pad 15, + bias + silu; bf16 in/out ----------------
#define TN_ 16
__global__ __launch_bounds__(256) void dwconv_kernel(const ushort* __restrict__ x,
                                                     const float* __restrict__ w,
                                                     const float* __restrict__ bias,
                                                     ushort* __restrict__ out) {
  const int bid = blockIdx.x;
  const int cb = bid & 3;
  const int nb = (bid >> 2) & 127;
  const int b  = bid >> 9;
  const int c = cb * 256 + threadIdx.x;
  const int n0 = nb * TN_;
  float win[TN_ + 30];
#pragma unroll
  for (int i = 0; i < TN_ + 30; i++) {
    int nn = n0 + i - 15;
    win[i] = (nn >= 0 && nn < N_) ? bf2f(x[(size_t)(b * N_ + nn) * INNER_ + c]) : 0.f;
  }
  float wc[31];
#pragma unroll
  for (int kk = 0; kk < 31; kk++) wc[kk] = w[c * 31 + kk];
  const float bsv = bias[c];
#pragma unroll
  for (int j = 0; j < TN_; j++) {
    float acc = bsv;
#pragma unroll
    for (int kk = 0; kk < 31; kk++) acc += win[j + kk] * wc[kk];
    acc = acc / (1.f + expf(-acc));
    out[(size_t)(b * N_ + n0 + j) * INNER_ + c] = f2bf(acc);
  }
}

// ---------------- host ----------------
extern "C" void kernel_launch(void* const* d_in, const int* in_sizes, int n_in,
                              void* d_out, int out_size, void* d_ws, size_t ws_size,
                              hipStream_t stream) {
  const float* in_x  = (const float*)d_in[0];
  const float* ln1_g = (const float*)d_in[1];
  const float* ln1_b = (const float*)d_in[2];
  const float* wq    = (const float*)d_in[3];
  const float* bq    = (const float*)d_in[4];
  const float* wk    = (const float*)d_in[5];
  const float* bk    = (const float*)d_in[6];
  const float* wv    = (const float*)d_in[7];
  const float* bv    = (const float*)d_in[8];
  const float* wo    = (const float*)d_in[9];
  const float* bo    = (const float*)d_in[10];
  const float* proj  = (const float*)d_in[11];
  const float* ln2_g = (const float*)d_in[12];
  const float* ln2_b = (const float*)d_in[13];
  const float* pw1_w = (const float*)d_in[14];
  const float* pw1_b = (const float*)d_in[15];
  const float* dw_w  = (const float*)d_in[16];
  const float* dw_b  = (const float*)d_in[17];
  const float* pw2_w = (const float*)d_in[18];
  const float* pw2_b = (const float*)d_in[19];

  char* cur = (char*)d_ws;
  auto alloc = [&](size_t bytes) { char* p = cur; cur += (bytes + 255) & ~(size_t)255; return p; };
  float*  x    = (float*)alloc((size_t)T_ * D_ * 4);
  ushort* p    = (ushort*)alloc((size_t)T_ * INNER_ * 2 * 2);      // glu+conv scratch
  float*  part = (float*)alloc((size_t)32 * NS_ * 5 * 4096 * 4);
  float*  kpart= (float*)alloc((size_t)32 * NS_ * 5 * 64 * 4);
  ushort* ctxb = (ushort*)alloc((size_t)32 * 288 * 64 * 2);
  float*  ksum = (float*)alloc((size_t)32 * PS_ * 4);
  ushort* h    = (ushort*)alloc((size_t)T_ * D_ * 2);
  ushort* qkv  = (ushort*)alloc((size_t)T_ * QKVS_ * 2);
  ushort* obuf = (ushort*)alloc((size_t)T_ * D_ * 2);
  ushort* wqkv_b = (ushort*)alloc((size_t)L_LAYERS * QKVS_ * 512 * 2);
  float*  bqkv   = (float*)alloc((size_t)L_LAYERS * QKVS_ * 4);
  ushort* wo_b = (ushort*)alloc((size_t)L_LAYERS * D_ * D_ * 2);
  ushort* pjp  = (ushort*)alloc((size_t)L_LAYERS * 320 * 64 * 2);
  ushort* p1_b = (ushort*)alloc((size_t)L_LAYERS * 2048 * D_ * 2);
  float*  pb1  = (float*)alloc((size_t)L_LAYERS * 2048 * 4);
  ushort* p2_b = (ushort*)alloc((size_t)L_LAYERS * D_ * INNER_ * 2);
  ushort* glu  = p;
  ushort* conv = p + (size_t)T_ * INNER_;

  pack_qkv_w<<<(L_LAYERS * 512 * 128 + 255) / 256, 256, 0, stream>>>((const float4*)wq, wqkv_b, 0);
  pack_qkv_w<<<(L_LAYERS * 512 * 128 + 255) / 256, 256, 0, stream>>>((const float4*)wk, wqkv_b, 512);
  pack_qkv_w<<<(L_LAYERS * 512 * 128 + 255) / 256, 256, 0, stream>>>((const float4*)wv, wqkv_b, 1024);
  pack_qkv_b<<<(L_LAYERS * QKVS_ + 255) / 256, 256, 0, stream>>>(bq, bk, bv, bqkv);
  pad_proj<<<(L_LAYERS * 320 * 64 + 255) / 256, 256, 0, stream>>>(proj, pjp);
  pack_pw1_w<<<(L_LAYERS * 2048 * 128 + 255) / 256, 256, 0, stream>>>((const float4*)pw1_w, p1_b);
  pack_pw1_b<<<(L_LAYERS * 2048 + 255) / 256, 256, 0, stream>>>(pw1_b, pb1);
  {
    int n4 = L_LAYERS * D_ * D_ / 4;
    f2bf4_kernel<<<(n4 + 255) / 256, 256, 0, stream>>>((const float4*)wo, wo_b, n4);
    n4 = L_LAYERS * D_ * INNER_ / 4;
    f2bf4_kernel<<<(n4 + 255) / 256, 256, 0, stream>>>((const float4*)pw2_w, p2_b, n4);
  }

  for (int l = 0; l < L_LAYERS; l++) {
    const ushort* wqkvl = wqkv_b + (size_t)l * QKVS_ * 512;
    const ushort* wol = wo_b + (size_t)l * D_ * D_;
    const ushort* pjl = pjp + (size_t)l * 320 * 64;
    const ushort* p1l = p1_b + (size_t)l * 2048 * D_;
    const ushort* p2l = p2_b + (size_t)l * D_ * INNER_;
    const float*  dwl = dw_w + (size_t)l * INNER_ * 31;
    const float*  xin = (l == 0) ? in_x : x;
    float* xout = (l == L_LAYERS - 1) ? (float*)d_out : x;

    ln_kernel<<<T_, 256, 0, stream>>>(xin, ln1_g + l * D_, ln1_b + l * D_, h);
    gemm_mfma<false, true, 0><<<dim3(T_ / 128, QKVS_ / 128), 256, 0, stream>>>(
        h, wqkvl, bqkv + (size_t)l * QKVS_, nullptr, qkv, D_, QKVS_);
    ctx_phi_mfma<<<dim3(32, 5, NS_), 256, 0, stream>>>(qkv, pjl, part, kpart);
    ctx_reduce<<<dim3(32, 5), 256, 0, stream>>>(part, kpart, ctxb, ksum);
    attn_fused<<<dim3(32, 32), 256, 0, stream>>>(qkv, pjl, ctxb, ksum, obuf);
    gemm_mfma<true, false, 0><<<dim3(T_ / 128, 4), 256, 0, stream>>>(
        obuf, wol, bo + l * D_, xin, x, D_, D_);
    ln_kernel<<<T_, 256, 0, stream>>>(x, ln2_g + l * D_, ln2_b + l * D_, h);
    gemm_mfma<false, true, 1><<<dim3(T_ / 128, 16), 256, 0, stream>>>(
        h, p1l, pb1 + (size_t)l * 2048, nullptr, glu, D_, INNER_);
    dwconv_kernel<<<B_ * (N_ / TN_) * 4, 256, 0, stream>>>(glu, dwl, dw_b + l * INNER_, conv);
    gemm_mfma<true, false, 0><<<dim3(T_ / 128, 4), 256, 0, stream>>>(
        conv, p2l, pw2_b + l * D_, x, xout, INNER_, D_);
  }
}